// Round 1
// baseline (14447.650 us; speedup 1.0000x reference)
//
#include <hip/hip_runtime.h>

#define D 256
#define K_OUT 32
#define L_LAYERS 4

// ---------------- init h: h[:,0] = x, rest 0 ----------------
__global__ void init_h(const float* __restrict__ x, float* __restrict__ h, int n) {
    int idx = blockIdx.x * blockDim.x + threadIdx.x;
    int total = n * D;
    for (int i = idx; i < total; i += gridDim.x * blockDim.x) {
        int d = i & (D - 1);
        h[i] = (d == 0) ? x[i >> 8] : 0.0f;
    }
}

// ---------------- m = h @ W  (N x 256) @ (256 x 256) ----------------
#define BM 64
#define BN 64
#define BK 32
__global__ __launch_bounds__(256) void gemm_m_kernel(const float* __restrict__ A,
                                                     const float* __restrict__ B,
                                                     float* __restrict__ C, int M) {
    __shared__ float As[BK][BM + 4];   // transposed, padded (16B-aligned rows)
    __shared__ float Bs[BK][BN];       // natural
    int tid = threadIdx.x;
    int tx = tid & 15;
    int ty = tid >> 4;
    int bm = blockIdx.x * BM;
    int bn = blockIdx.y * BN;
    float acc[4][4] = {};
    for (int kb = 0; kb < D; kb += BK) {
        #pragma unroll
        for (int i = 0; i < 2; i++) {
            int lin = tid + i * 256;          // 0..511
            int row = lin >> 3;               // 8 float4 per 32-col row
            int c4  = (lin & 7) << 2;
            float4 v = make_float4(0.f, 0.f, 0.f, 0.f);
            int gr = bm + row;
            if (gr < M) v = *reinterpret_cast<const float4*>(&A[(size_t)gr * D + kb + c4]);
            As[c4 + 0][row] = v.x;
            As[c4 + 1][row] = v.y;
            As[c4 + 2][row] = v.z;
            As[c4 + 3][row] = v.w;
        }
        #pragma unroll
        for (int i = 0; i < 2; i++) {
            int lin = tid + i * 256;
            int row = lin >> 4;               // 16 float4 per 64-col row
            int c4  = (lin & 15) << 2;
            float4 v = *reinterpret_cast<const float4*>(&B[(size_t)(kb + row) * D + bn + c4]);
            *reinterpret_cast<float4*>(&Bs[row][c4]) = v;
        }
        __syncthreads();
        #pragma unroll
        for (int kk = 0; kk < BK; kk++) {
            float a[4], b[4];
            *reinterpret_cast<float4*>(a) = *reinterpret_cast<const float4*>(&As[kk][ty * 4]);
            *reinterpret_cast<float4*>(b) = *reinterpret_cast<const float4*>(&Bs[kk][tx * 4]);
            #pragma unroll
            for (int i = 0; i < 4; i++)
                #pragma unroll
                for (int j = 0; j < 4; j++)
                    acc[i][j] += a[i] * b[j];
        }
        __syncthreads();
    }
    #pragma unroll
    for (int i = 0; i < 4; i++) {
        int gr = bm + ty * 4 + i;
        if (gr < M) {
            *reinterpret_cast<float4*>(&C[(size_t)gr * D + bn + tx * 4]) =
                make_float4(acc[i][0], acc[i][1], acc[i][2], acc[i][3]);
        }
    }
}

// ---------------- scatter: agg[dst] += ea * m[src], one wave per edge ----------------
__global__ __launch_bounds__(256) void scatter_kernel(const float* __restrict__ m,
                                                      const int* __restrict__ src,
                                                      const int* __restrict__ dst,
                                                      const float* __restrict__ ea,
                                                      float* __restrict__ agg, int E) {
    int wid  = (blockIdx.x * blockDim.x + threadIdx.x) >> 6;
    int lane = threadIdx.x & 63;
    int nw   = (gridDim.x * blockDim.x) >> 6;
    for (int e = wid; e < E; e += nw) {
        int s = src[e], d0 = dst[e];
        float a = ea[e];
        float4 v = *reinterpret_cast<const float4*>(&m[(size_t)s * D + lane * 4]);
        float* dest = &agg[(size_t)d0 * D + lane * 4];
        atomicAdd(dest + 0, a * v.x);
        atomicAdd(dest + 1, a * v.y);
        atomicAdd(dest + 2, a * v.z);
        atomicAdd(dest + 3, a * v.w);
    }
}

// ---------------- fused GRU: 6 dot products + pointwise, writes hout ----------------
#define GM 64
#define GN 32
#define GK 32
__global__ __launch_bounds__(256) void gru_kernel(const float* __restrict__ agg,
                                                  const float* __restrict__ h,
                                                  const float* __restrict__ w_ih,
                                                  const float* __restrict__ w_hh,
                                                  const float* __restrict__ b_ih,
                                                  const float* __restrict__ b_hh,
                                                  float* __restrict__ hout, int M) {
    __shared__ float Aa[GK][GM + 4];
    __shared__ float Ah[GK][GM + 4];
    __shared__ float Bs[6][GK][GN + 4];
    int tid = threadIdx.x;
    int tx = tid & 15;     // 16 * 2 cols = 32
    int ty = tid >> 4;     // 16 * 4 rows = 64
    int bm = blockIdx.x * GM;
    int bn = blockIdx.y * GN;
    float acc[6][4][2] = {};
    for (int kb = 0; kb < D; kb += GK) {
        #pragma unroll
        for (int i = 0; i < 2; i++) {
            int lin = tid + i * 256;
            int row = lin >> 3;
            int c4  = (lin & 7) << 2;
            int gr = bm + row;
            float4 va = make_float4(0.f,0.f,0.f,0.f), vh = va;
            if (gr < M) {
                va = *reinterpret_cast<const float4*>(&agg[(size_t)gr * D + kb + c4]);
                vh = *reinterpret_cast<const float4*>(&h[(size_t)gr * D + kb + c4]);
            }
            Aa[c4+0][row]=va.x; Aa[c4+1][row]=va.y; Aa[c4+2][row]=va.z; Aa[c4+3][row]=va.w;
            Ah[c4+0][row]=vh.x; Ah[c4+1][row]=vh.y; Ah[c4+2][row]=vh.z; Ah[c4+3][row]=vh.w;
        }
        int drow = tid >> 3;            // 0..31 (d within tile)
        int c4   = (tid & 7) << 2;      // k offset
        #pragma unroll
        for (int g = 0; g < 6; g++) {
            const float* w = (g < 3) ? w_ih : w_hh;
            int go = (g % 3) * D;
            float4 v = *reinterpret_cast<const float4*>(
                &w[(size_t)(go + bn + drow) * D + kb + c4]);
            Bs[g][c4+0][drow] = v.x;
            Bs[g][c4+1][drow] = v.y;
            Bs[g][c4+2][drow] = v.z;
            Bs[g][c4+3][drow] = v.w;
        }
        __syncthreads();
        #pragma unroll
        for (int kk = 0; kk < GK; kk++) {
            float aa[4], ah[4];
            *reinterpret_cast<float4*>(aa) = *reinterpret_cast<const float4*>(&Aa[kk][ty*4]);
            *reinterpret_cast<float4*>(ah) = *reinterpret_cast<const float4*>(&Ah[kk][ty*4]);
            float b[6][2];
            #pragma unroll
            for (int g = 0; g < 6; g++) {
                float2 bv = *reinterpret_cast<const float2*>(&Bs[g][kk][tx*2]);
                b[g][0] = bv.x; b[g][1] = bv.y;
            }
            #pragma unroll
            for (int g = 0; g < 6; g++)
                #pragma unroll
                for (int i = 0; i < 4; i++)
                    #pragma unroll
                    for (int j = 0; j < 2; j++)
                        acc[g][i][j] += ((g < 3) ? aa[i] : ah[i]) * b[g][j];
        }
        __syncthreads();
    }
    #pragma unroll
    for (int i = 0; i < 4; i++) {
        int n = bm + ty * 4 + i;
        if (n >= M) continue;
        #pragma unroll
        for (int j = 0; j < 2; j++) {
            int d = bn + tx * 2 + j;
            float ir = acc[0][i][j] + b_ih[d];
            float iz = acc[1][i][j] + b_ih[D + d];
            float in_ = acc[2][i][j] + b_ih[2*D + d];
            float hr = acc[3][i][j] + b_hh[d];
            float hz = acc[4][i][j] + b_hh[D + d];
            float hn = acc[5][i][j] + b_hh[2*D + d];
            float r = 1.f / (1.f + __expf(-(ir + hr)));
            float z = 1.f / (1.f + __expf(-(iz + hz)));
            float nn = tanhf(in_ + r * hn);
            float hv = h[(size_t)n * D + d];
            hout[(size_t)n * D + d] = (1.f - z) * nn + z * hv;
        }
    }
}

// ---------------- readout + softmax ----------------
__global__ __launch_bounds__(256) void readout_kernel(const float* __restrict__ h,
                                                      const float* __restrict__ w_ro,
                                                      const float* __restrict__ b_ro,
                                                      float* __restrict__ out, int M) {
    __shared__ float ws_[D * K_OUT];
    for (int i = threadIdx.x; i < D * K_OUT; i += 256) ws_[i] = w_ro[i];
    __syncthreads();
    int group = threadIdx.x >> 5;
    int col   = threadIdx.x & 31;
    int node  = blockIdx.x * 8 + group;
    if (node >= M) return;
    float acc = b_ro[col];
    const float* hrow = &h[(size_t)node * D];
    #pragma unroll 8
    for (int k = 0; k < D; k++) acc += hrow[k] * ws_[k * K_OUT + col];
    float mx = acc;
    #pragma unroll
    for (int off = 16; off > 0; off >>= 1) mx = fmaxf(mx, __shfl_xor(mx, off, 32));
    float e = __expf(acc - mx);
    float s = e;
    #pragma unroll
    for (int off = 16; off > 0; off >>= 1) s += __shfl_xor(s, off, 32);
    out[(size_t)node * K_OUT + col] = e / s;
}

extern "C" void kernel_launch(void* const* d_in, const int* in_sizes, int n_in,
                              void* d_out, int out_size, void* d_ws, size_t ws_size,
                              hipStream_t stream) {
    const float* x      = (const float*)d_in[0];
    const int*   ei     = (const int*)d_in[1];
    const float* ea     = (const float*)d_in[2];
    const float* weight = (const float*)d_in[3];
    const float* w_ih   = (const float*)d_in[4];
    const float* w_hh   = (const float*)d_in[5];
    const float* b_ih   = (const float*)d_in[6];
    const float* b_hh   = (const float*)d_in[7];
    const float* w_ro   = (const float*)d_in[8];
    const float* b_ro   = (const float*)d_in[9];
    float* out = (float*)d_out;

    int N = in_sizes[0];          // 50000
    int E = in_sizes[2];          // 800000 (edge_attr count)
    const int* src = ei;
    const int* dst = ei + E;

    size_t ND = (size_t)N * D;
    float* hA   = (float*)d_ws;
    float* hB   = hA + ND;
    float* mbuf = hB + ND;
    float* agg  = mbuf + ND;

    init_h<<<2048, 256, 0, stream>>>(x, hA, N);

    float* hcur = hA;
    float* hnext = hB;
    dim3 ggemm((N + BM - 1) / BM, D / BN);
    dim3 ggru((N + GM - 1) / GM, D / GN);
    for (int l = 0; l < L_LAYERS; l++) {
        gemm_m_kernel<<<ggemm, 256, 0, stream>>>(hcur, weight + (size_t)l * D * D, mbuf, N);
        hipMemsetAsync(agg, 0, ND * sizeof(float), stream);
        scatter_kernel<<<4096, 256, 0, stream>>>(mbuf, src, dst, ea, agg, E);
        gru_kernel<<<ggru, 256, 0, stream>>>(agg, hcur, w_ih, w_hh, b_ih, b_hh, hnext, N);
        float* t = hcur; hcur = hnext; hnext = t;
    }
    readout_kernel<<<(N + 7) / 8, 256, 0, stream>>>(hcur, w_ro, b_ro, out, N);
}

// Round 2
// 3992.837 us; speedup vs baseline: 3.6184x; 3.6184x over previous
//
#include <hip/hip_runtime.h>

#define D 256
#define K_OUT 32
#define L_LAYERS 4

// ---------------- init h: h[:,0] = x, rest 0 ----------------
__global__ void init_h(const float* __restrict__ x, float* __restrict__ h, int n) {
    int idx = blockIdx.x * blockDim.x + threadIdx.x;
    int total = n * D;
    for (int i = idx; i < total; i += gridDim.x * blockDim.x) {
        int d = i & (D - 1);
        h[i] = (d == 0) ? x[i >> 8] : 0.0f;
    }
}

// ---------------- CSR build: histogram / scan / reorder ----------------
__global__ __launch_bounds__(256) void hist_kernel(const int* __restrict__ dst,
                                                   int* __restrict__ cnt, int E) {
    int idx = blockIdx.x * blockDim.x + threadIdx.x;
    for (int e = idx; e < E; e += gridDim.x * blockDim.x)
        atomicAdd(&cnt[dst[e]], 1);
}

// single block, 1024 threads: exclusive scan of cnt[0..n) -> rowptr, cursor; rowptr[n]=total
__global__ __launch_bounds__(1024) void scan_kernel(const int* __restrict__ cnt,
                                                    int* __restrict__ rowptr,
                                                    int* __restrict__ cursor, int n) {
    __shared__ int sdata[1024];
    int t = threadIdx.x;
    int chunk = (n + 1023) / 1024;
    int start = t * chunk;
    int end = start + chunk; if (end > n) end = n;
    int s = 0;
    for (int i = start; i < end && i >= 0; i++) s += cnt[i];
    sdata[t] = s;
    __syncthreads();
    for (int off = 1; off < 1024; off <<= 1) {
        int v = (t >= off) ? sdata[t - off] : 0;
        __syncthreads();
        sdata[t] += v;
        __syncthreads();
    }
    int base = sdata[t] - s;   // exclusive
    for (int i = start; i < end; i++) {
        rowptr[i] = base;
        cursor[i] = base;
        base += cnt[i];
    }
    if (end == n && start <= n) rowptr[n] = base;
}

__global__ __launch_bounds__(256) void reorder_kernel(const int* __restrict__ src,
                                                      const int* __restrict__ dst,
                                                      const float* __restrict__ ea,
                                                      int* __restrict__ cursor,
                                                      int* __restrict__ esrc,
                                                      float* __restrict__ eval, int E) {
    int idx = blockIdx.x * blockDim.x + threadIdx.x;
    for (int e = idx; e < E; e += gridDim.x * blockDim.x) {
        int slot = atomicAdd(&cursor[dst[e]], 1);
        esrc[slot] = src[e];
        eval[slot] = ea[e];
    }
}

// ---------------- m = h @ W  (N x 256) @ (256 x 256) ----------------
#define BM 64
#define BN 64
#define BK 32
__global__ __launch_bounds__(256) void gemm_m_kernel(const float* __restrict__ A,
                                                     const float* __restrict__ B,
                                                     float* __restrict__ C, int M) {
    __shared__ float As[BK][BM + 4];
    __shared__ float Bs[BK][BN];
    int tid = threadIdx.x;
    int tx = tid & 15;
    int ty = tid >> 4;
    int bm = blockIdx.x * BM;
    int bn = blockIdx.y * BN;
    float acc[4][4] = {};
    for (int kb = 0; kb < D; kb += BK) {
        #pragma unroll
        for (int i = 0; i < 2; i++) {
            int lin = tid + i * 256;
            int row = lin >> 3;
            int c4  = (lin & 7) << 2;
            float4 v = make_float4(0.f, 0.f, 0.f, 0.f);
            int gr = bm + row;
            if (gr < M) v = *reinterpret_cast<const float4*>(&A[(size_t)gr * D + kb + c4]);
            As[c4 + 0][row] = v.x;
            As[c4 + 1][row] = v.y;
            As[c4 + 2][row] = v.z;
            As[c4 + 3][row] = v.w;
        }
        #pragma unroll
        for (int i = 0; i < 2; i++) {
            int lin = tid + i * 256;
            int row = lin >> 4;
            int c4  = (lin & 15) << 2;
            float4 v = *reinterpret_cast<const float4*>(&B[(size_t)(kb + row) * D + bn + c4]);
            *reinterpret_cast<float4*>(&Bs[row][c4]) = v;
        }
        __syncthreads();
        #pragma unroll
        for (int kk = 0; kk < BK; kk++) {
            float a[4], b[4];
            *reinterpret_cast<float4*>(a) = *reinterpret_cast<const float4*>(&As[kk][ty * 4]);
            *reinterpret_cast<float4*>(b) = *reinterpret_cast<const float4*>(&Bs[kk][tx * 4]);
            #pragma unroll
            for (int i = 0; i < 4; i++)
                #pragma unroll
                for (int j = 0; j < 4; j++)
                    acc[i][j] += a[i] * b[j];
        }
        __syncthreads();
    }
    #pragma unroll
    for (int i = 0; i < 4; i++) {
        int gr = bm + ty * 4 + i;
        if (gr < M) {
            *reinterpret_cast<float4*>(&C[(size_t)gr * D + bn + tx * 4]) =
                make_float4(acc[i][0], acc[i][1], acc[i][2], acc[i][3]);
        }
    }
}

// ---------------- gather: agg[n] = sum_e eval[e] * m[esrc[e]], wave per node ----------------
__global__ __launch_bounds__(256) void gather_kernel(const float* __restrict__ m,
                                                     const int* __restrict__ rowptr,
                                                     const int* __restrict__ esrc,
                                                     const float* __restrict__ eval,
                                                     float* __restrict__ agg, int n) {
    int node = (blockIdx.x * blockDim.x + threadIdx.x) >> 6;
    int lane = threadIdx.x & 63;
    if (node >= n) return;
    int beg = rowptr[node];
    int end = rowptr[node + 1];
    float4 acc = make_float4(0.f, 0.f, 0.f, 0.f);
    for (int e = beg; e < end; e++) {
        int s = esrc[e];
        float a = eval[e];
        float4 v = *reinterpret_cast<const float4*>(&m[(size_t)s * D + lane * 4]);
        acc.x += a * v.x;
        acc.y += a * v.y;
        acc.z += a * v.z;
        acc.w += a * v.w;
    }
    *reinterpret_cast<float4*>(&agg[(size_t)node * D + lane * 4]) = acc;
}

// ---------------- fused GRU: 6 dot products + pointwise, writes hout ----------------
#define GM 64
#define GN 32
#define GK 32
__global__ __launch_bounds__(256) void gru_kernel(const float* __restrict__ agg,
                                                  const float* __restrict__ h,
                                                  const float* __restrict__ w_ih,
                                                  const float* __restrict__ w_hh,
                                                  const float* __restrict__ b_ih,
                                                  const float* __restrict__ b_hh,
                                                  float* __restrict__ hout, int M) {
    __shared__ float Aa[GK][GM + 4];
    __shared__ float Ah[GK][GM + 4];
    __shared__ float Bs[6][GK][GN + 4];
    int tid = threadIdx.x;
    int tx = tid & 15;
    int ty = tid >> 4;
    int bm = blockIdx.x * GM;
    int bn = blockIdx.y * GN;
    float acc[6][4][2] = {};
    for (int kb = 0; kb < D; kb += GK) {
        #pragma unroll
        for (int i = 0; i < 2; i++) {
            int lin = tid + i * 256;
            int row = lin >> 3;
            int c4  = (lin & 7) << 2;
            int gr = bm + row;
            float4 va = make_float4(0.f,0.f,0.f,0.f), vh = va;
            if (gr < M) {
                va = *reinterpret_cast<const float4*>(&agg[(size_t)gr * D + kb + c4]);
                vh = *reinterpret_cast<const float4*>(&h[(size_t)gr * D + kb + c4]);
            }
            Aa[c4+0][row]=va.x; Aa[c4+1][row]=va.y; Aa[c4+2][row]=va.z; Aa[c4+3][row]=va.w;
            Ah[c4+0][row]=vh.x; Ah[c4+1][row]=vh.y; Ah[c4+2][row]=vh.z; Ah[c4+3][row]=vh.w;
        }
        int drow = tid >> 3;
        int c4   = (tid & 7) << 2;
        #pragma unroll
        for (int g = 0; g < 6; g++) {
            const float* w = (g < 3) ? w_ih : w_hh;
            int go = (g % 3) * D;
            float4 v = *reinterpret_cast<const float4*>(
                &w[(size_t)(go + bn + drow) * D + kb + c4]);
            Bs[g][c4+0][drow] = v.x;
            Bs[g][c4+1][drow] = v.y;
            Bs[g][c4+2][drow] = v.z;
            Bs[g][c4+3][drow] = v.w;
        }
        __syncthreads();
        #pragma unroll
        for (int kk = 0; kk < GK; kk++) {
            float aa[4], ah[4];
            *reinterpret_cast<float4*>(aa) = *reinterpret_cast<const float4*>(&Aa[kk][ty*4]);
            *reinterpret_cast<float4*>(ah) = *reinterpret_cast<const float4*>(&Ah[kk][ty*4]);
            float b[6][2];
            #pragma unroll
            for (int g = 0; g < 6; g++) {
                float2 bv = *reinterpret_cast<const float2*>(&Bs[g][kk][tx*2]);
                b[g][0] = bv.x; b[g][1] = bv.y;
            }
            #pragma unroll
            for (int g = 0; g < 6; g++)
                #pragma unroll
                for (int i = 0; i < 4; i++)
                    #pragma unroll
                    for (int j = 0; j < 2; j++)
                        acc[g][i][j] += ((g < 3) ? aa[i] : ah[i]) * b[g][j];
        }
        __syncthreads();
    }
    #pragma unroll
    for (int i = 0; i < 4; i++) {
        int n = bm + ty * 4 + i;
        if (n >= M) continue;
        #pragma unroll
        for (int j = 0; j < 2; j++) {
            int d = bn + tx * 2 + j;
            float ir = acc[0][i][j] + b_ih[d];
            float iz = acc[1][i][j] + b_ih[D + d];
            float in_ = acc[2][i][j] + b_ih[2*D + d];
            float hr = acc[3][i][j] + b_hh[d];
            float hz = acc[4][i][j] + b_hh[D + d];
            float hn = acc[5][i][j] + b_hh[2*D + d];
            float r = 1.f / (1.f + __expf(-(ir + hr)));
            float z = 1.f / (1.f + __expf(-(iz + hz)));
            float nn = tanhf(in_ + r * hn);
            float hv = h[(size_t)n * D + d];
            hout[(size_t)n * D + d] = (1.f - z) * nn + z * hv;
        }
    }
}

// ---------------- readout + softmax ----------------
__global__ __launch_bounds__(256) void readout_kernel(const float* __restrict__ h,
                                                      const float* __restrict__ w_ro,
                                                      const float* __restrict__ b_ro,
                                                      float* __restrict__ out, int M) {
    __shared__ float ws_[D * K_OUT];
    for (int i = threadIdx.x; i < D * K_OUT; i += 256) ws_[i] = w_ro[i];
    __syncthreads();
    int group = threadIdx.x >> 5;
    int col   = threadIdx.x & 31;
    int node  = blockIdx.x * 8 + group;
    if (node >= M) return;
    float acc = b_ro[col];
    const float* hrow = &h[(size_t)node * D];
    #pragma unroll 8
    for (int k = 0; k < D; k++) acc += hrow[k] * ws_[k * K_OUT + col];
    float mx = acc;
    #pragma unroll
    for (int off = 16; off > 0; off >>= 1) mx = fmaxf(mx, __shfl_xor(mx, off, 32));
    float e = __expf(acc - mx);
    float s = e;
    #pragma unroll
    for (int off = 16; off > 0; off >>= 1) s += __shfl_xor(s, off, 32);
    out[(size_t)node * K_OUT + col] = e / s;
}

extern "C" void kernel_launch(void* const* d_in, const int* in_sizes, int n_in,
                              void* d_out, int out_size, void* d_ws, size_t ws_size,
                              hipStream_t stream) {
    const float* x      = (const float*)d_in[0];
    const int*   ei     = (const int*)d_in[1];
    const float* ea     = (const float*)d_in[2];
    const float* weight = (const float*)d_in[3];
    const float* w_ih   = (const float*)d_in[4];
    const float* w_hh   = (const float*)d_in[5];
    const float* b_ih   = (const float*)d_in[6];
    const float* b_hh   = (const float*)d_in[7];
    const float* w_ro   = (const float*)d_in[8];
    const float* b_ro   = (const float*)d_in[9];
    float* out = (float*)d_out;

    int N = in_sizes[0];          // 50000
    int E = in_sizes[2];          // 800000
    const int* src = ei;
    const int* dst = ei + E;

    size_t ND = (size_t)N * D;
    float* hA   = (float*)d_ws;
    float* hB   = hA + ND;
    float* mbuf = hB + ND;
    float* agg  = mbuf + ND;
    int*   cnt    = (int*)(agg + ND);
    int*   rowptr = cnt + (N + 1);
    int*   cursor = rowptr + (N + 1);
    int*   esrc   = cursor + (N + 1);
    float* eval   = (float*)(esrc + E);

    // ---- CSR build (edge_index constant across layers) ----
    hipMemsetAsync(cnt, 0, (N + 1) * sizeof(int), stream);
    hist_kernel<<<1024, 256, 0, stream>>>(dst, cnt, E);
    scan_kernel<<<1, 1024, 0, stream>>>(cnt, rowptr, cursor, N);
    reorder_kernel<<<1024, 256, 0, stream>>>(src, dst, ea, cursor, esrc, eval, E);

    init_h<<<2048, 256, 0, stream>>>(x, hA, N);

    float* hcur = hA;
    float* hnext = hB;
    dim3 ggemm((N + BM - 1) / BM, D / BN);
    dim3 ggru((N + GM - 1) / GM, D / GN);
    int gather_blocks = (N * 64 + 255) / 256;
    for (int l = 0; l < L_LAYERS; l++) {
        gemm_m_kernel<<<ggemm, 256, 0, stream>>>(hcur, weight + (size_t)l * D * D, mbuf, N);
        gather_kernel<<<gather_blocks, 256, 0, stream>>>(mbuf, rowptr, esrc, eval, agg, N);
        gru_kernel<<<ggru, 256, 0, stream>>>(agg, hcur, w_ih, w_hh, b_ih, b_hh, hnext, N);
        float* t = hcur; hcur = hnext; hnext = t;
    }
    readout_kernel<<<(N + 7) / 8, 256, 0, stream>>>(hcur, w_ro, b_ro, out, N);
}

// Round 4
// 3230.180 us; speedup vs baseline: 4.4727x; 1.2361x over previous
//
#include <hip/hip_runtime.h>

#define D 256
#define K_OUT 32
#define L_LAYERS 4
#define NGATE 768

__device__ __forceinline__ float sigm(float v) { return 1.f / (1.f + __expf(-v)); }

// ---------------- CSR build: histogram / scan / reorder ----------------
__global__ __launch_bounds__(256) void hist_kernel(const int* __restrict__ dst,
                                                   int* __restrict__ cnt, int E) {
    int idx = blockIdx.x * blockDim.x + threadIdx.x;
    for (int e = idx; e < E; e += gridDim.x * blockDim.x)
        atomicAdd(&cnt[dst[e]], 1);
}

__global__ __launch_bounds__(1024) void scan_kernel(const int* __restrict__ cnt,
                                                    int* __restrict__ rowptr,
                                                    int* __restrict__ cursor, int n) {
    __shared__ int sdata[1024];
    int t = threadIdx.x;
    int chunk = (n + 1023) / 1024;
    int start = t * chunk;
    int end = start + chunk; if (end > n) end = n;
    int s = 0;
    for (int i = start; i < end; i++) s += cnt[i];
    sdata[t] = s;
    __syncthreads();
    for (int off = 1; off < 1024; off <<= 1) {
        int v = (t >= off) ? sdata[t - off] : 0;
        __syncthreads();
        sdata[t] += v;
        __syncthreads();
    }
    int base = sdata[t] - s;
    for (int i = start; i < end; i++) {
        rowptr[i] = base;
        cursor[i] = base;
        base += cnt[i];
    }
    if (end == n && start <= n) rowptr[n] = base;
}

__global__ __launch_bounds__(256) void reorder_kernel(const int* __restrict__ src,
                                                      const int* __restrict__ dst,
                                                      const float* __restrict__ ea,
                                                      int* __restrict__ cursor,
                                                      int* __restrict__ esrc,
                                                      float* __restrict__ eval, int E) {
    int idx = blockIdx.x * blockDim.x + threadIdx.x;
    for (int e = idx; e < E; e += gridDim.x * blockDim.x) {
        int slot = atomicAdd(&cursor[dst[e]], 1);
        esrc[slot] = src[e];
        eval[slot] = ea[e];
    }
}

// ---------------- Bprep[l][k][n], k<256: weight[l] @ w_ih^T ----------------
__global__ __launch_bounds__(256) void prep_wih_kernel(const float* __restrict__ weight,
                                                       const float* __restrict__ w_ih,
                                                       float* __restrict__ Bprep) {
    int l = blockIdx.z;
    const float* A = weight + (size_t)l * D * D;
    float* Cdst = Bprep + (size_t)l * 512 * NGATE;
    __shared__ float As[32][64 + 4];
    __shared__ float Bs[32][64 + 4];
    int tid = threadIdx.x;
    int tx = tid & 15, ty = tid >> 4;
    int bk = blockIdx.x * 64;
    int bn = blockIdx.y * 64;
    float acc[4][4] = {};
    for (int jb = 0; jb < D; jb += 32) {
        #pragma unroll
        for (int i = 0; i < 2; i++) {
            int lin = tid + i * 256;
            int row = lin >> 3;
            int c4 = (lin & 7) << 2;
            float4 v = *(const float4*)&A[(size_t)(bk + row) * D + jb + c4];
            As[c4+0][row]=v.x; As[c4+1][row]=v.y; As[c4+2][row]=v.z; As[c4+3][row]=v.w;
            float4 w = *(const float4*)&w_ih[(size_t)(bn + row) * D + jb + c4];
            Bs[c4+0][row]=w.x; Bs[c4+1][row]=w.y; Bs[c4+2][row]=w.z; Bs[c4+3][row]=w.w;
        }
        __syncthreads();
        #pragma unroll
        for (int jj = 0; jj < 32; jj++) {
            float a[4], b[4];
            *(float4*)a = *(const float4*)&As[jj][ty*4];
            *(float4*)b = *(const float4*)&Bs[jj][tx*4];
            #pragma unroll
            for (int i = 0; i < 4; i++)
                #pragma unroll
                for (int j = 0; j < 4; j++)
                    acc[i][j] += a[i] * b[j];
        }
        __syncthreads();
    }
    #pragma unroll
    for (int i = 0; i < 4; i++)
        *(float4*)&Cdst[(size_t)(bk + ty*4 + i) * NGATE + bn + tx*4] =
            make_float4(acc[i][0], acc[i][1], acc[i][2], acc[i][3]);
}

// ---------------- Bprep[l][256+k][n] = w_hh[n][k], all layers ----------------
__global__ __launch_bounds__(256) void prep_whh_kernel(const float* __restrict__ w_hh,
                                                       float* __restrict__ Bprep) {
    __shared__ float t[32][33];
    int bk = blockIdx.x * 32;
    int bn = blockIdx.y * 32;
    int txx = threadIdx.x & 31, tyy = threadIdx.x >> 5;
    for (int r = tyy; r < 32; r += 8)
        t[r][txx] = w_hh[(size_t)(bn + r) * D + bk + txx];
    __syncthreads();
    #pragma unroll
    for (int l = 0; l < L_LAYERS; l++) {
        float* dstB = Bprep + (size_t)l * 512 * NGATE;
        for (int r = tyy; r < 32; r += 8)
            dstB[(size_t)(256 + bk + r) * NGATE + bn + txx] = t[txx][r];
    }
}

// ---------------- scalar gather: sx[n] = sum ea * x[src] ----------------
__global__ __launch_bounds__(256) void sgather_kernel(const float* __restrict__ x,
                                                      const int* __restrict__ rowptr,
                                                      const int* __restrict__ esrc,
                                                      const float* __restrict__ eval,
                                                      float* __restrict__ sx, int n) {
    int node = blockIdx.x * blockDim.x + threadIdx.x;
    if (node >= n) return;
    float s = 0.f;
    int end = rowptr[node + 1];
    for (int e = rowptr[node]; e < end; e++) s += eval[e] * x[esrc[e]];
    sx[node] = s;
}

// ---------------- layer 0: rank-2 GEMM + GRU epilogue ----------------
__global__ __launch_bounds__(256) void layer0_kernel(const float* __restrict__ x,
                                                     const float* __restrict__ sx,
                                                     const float* __restrict__ Bp,
                                                     const float* __restrict__ b_ih,
                                                     const float* __restrict__ b_hh,
                                                     float* __restrict__ hout, int M) {
    int node = blockIdx.x * 4 + (threadIdx.x >> 6);
    if (node >= M) return;
    int d0 = (threadIdx.x & 63) * 4;
    float sxn = sx[node], xn = x[node];
    const float* B0 = Bp;                       // row k=0 (agg col 0)
    const float* B1 = Bp + (size_t)256 * NGATE; // row k=256 (h col 0)
    float4 r0 = *(const float4*)&B0[d0];
    float4 r1 = *(const float4*)&B1[d0];
    float4 z0 = *(const float4*)&B0[256 + d0];
    float4 z1 = *(const float4*)&B1[256 + d0];
    float4 n0 = *(const float4*)&B0[512 + d0];
    float4 n1 = *(const float4*)&B1[512 + d0];
    float4 bir = *(const float4*)&b_ih[d0];
    float4 biz = *(const float4*)&b_ih[256 + d0];
    float4 bin = *(const float4*)&b_ih[512 + d0];
    float4 bhr = *(const float4*)&b_hh[d0];
    float4 bhz = *(const float4*)&b_hh[256 + d0];
    float4 bhn = *(const float4*)&b_hh[512 + d0];
    float rr[4], zz[4], ni[4], nh[4], o[4];
    rr[0]=sxn*r0.x+xn*r1.x+bir.x+bhr.x; rr[1]=sxn*r0.y+xn*r1.y+bir.y+bhr.y;
    rr[2]=sxn*r0.z+xn*r1.z+bir.z+bhr.z; rr[3]=sxn*r0.w+xn*r1.w+bir.w+bhr.w;
    zz[0]=sxn*z0.x+xn*z1.x+biz.x+bhz.x; zz[1]=sxn*z0.y+xn*z1.y+biz.y+bhz.y;
    zz[2]=sxn*z0.z+xn*z1.z+biz.z+bhz.z; zz[3]=sxn*z0.w+xn*z1.w+biz.w+bhz.w;
    ni[0]=sxn*n0.x+bin.x; ni[1]=sxn*n0.y+bin.y; ni[2]=sxn*n0.z+bin.z; ni[3]=sxn*n0.w+bin.w;
    nh[0]=xn*n1.x+bhn.x;  nh[1]=xn*n1.y+bhn.y;  nh[2]=xn*n1.z+bhn.z;  nh[3]=xn*n1.w+bhn.w;
    #pragma unroll
    for (int j = 0; j < 4; j++) {
        float r = sigm(rr[j]);
        float z = sigm(zz[j]);
        float nn = tanhf(ni[j] + r * nh[j]);
        float hp = (d0 + j == 0) ? xn : 0.f;
        o[j] = (1.f - z) * nn + z * hp;
    }
    *(float4*)&hout[(size_t)node * D + d0] = make_float4(o[0], o[1], o[2], o[3]);
}

// ---------------- gather: agg[n] = sum eval * h[esrc], wave per node ----------------
__global__ __launch_bounds__(256) void gather_kernel(const float* __restrict__ m,
                                                     const int* __restrict__ rowptr,
                                                     const int* __restrict__ esrc,
                                                     const float* __restrict__ eval,
                                                     float* __restrict__ agg, int n) {
    int node = (blockIdx.x * blockDim.x + threadIdx.x) >> 6;
    int lane = threadIdx.x & 63;
    if (node >= n) return;
    int beg = rowptr[node];
    int end = rowptr[node + 1];
    float4 acc = make_float4(0.f, 0.f, 0.f, 0.f);
    for (int e = beg; e < end; e++) {
        int s = esrc[e];
        float a = eval[e];
        float4 v = *reinterpret_cast<const float4*>(&m[(size_t)s * D + lane * 4]);
        acc.x += a * v.x;
        acc.y += a * v.y;
        acc.z += a * v.z;
        acc.w += a * v.w;
    }
    *reinterpret_cast<float4*>(&agg[(size_t)node * D + lane * 4]) = acc;
}

// ---------------- fused GRU GEMM: [agg|h](N x 512) @ Bprep(512 x 768) + epilogue ----------------
#define FM 64
#define FN 64
#define FK 32
__global__ __launch_bounds__(256) void fused_gru_kernel(const float* __restrict__ agg,
                                                        const float* __restrict__ h,
                                                        const float* __restrict__ Bp,
                                                        const float* __restrict__ b_ih,
                                                        const float* __restrict__ b_hh,
                                                        float* __restrict__ hout, int M) {
    __shared__ float As[FK][FM + 4];
    __shared__ float Bs[3][FK][FN];
    int tid = threadIdx.x;
    int tx = tid & 15, ty = tid >> 4;
    int bm = blockIdx.x * FM, bn = blockIdx.y * FN;
    float accR[4][4] = {}, accZ[4][4] = {}, accNi[4][4] = {}, accNh[4][4] = {};

#define KHALF(ASRC, ROWOFF, ACCN)                                                   \
    for (int kb = 0; kb < D; kb += FK) {                                            \
        _Pragma("unroll")                                                           \
        for (int i = 0; i < 2; i++) {                                               \
            int lin = tid + i * 256;                                                \
            int row = lin >> 3;                                                     \
            int c4 = (lin & 7) << 2;                                                \
            float4 v = make_float4(0.f, 0.f, 0.f, 0.f);                             \
            int gr = bm + row;                                                      \
            if (gr < M) v = *(const float4*)&ASRC[(size_t)gr * D + kb + c4];        \
            As[c4+0][row] = v.x; As[c4+1][row] = v.y;                               \
            As[c4+2][row] = v.z; As[c4+3][row] = v.w;                               \
        }                                                                           \
        _Pragma("unroll")                                                           \
        for (int i = 0; i < 6; i++) {                                               \
            int lin = tid + i * 256;                                                \
            int p = lin >> 9;                                                       \
            int rem = lin & 511;                                                    \
            int krow = rem >> 4;                                                    \
            int c4 = (rem & 15) << 2;                                               \
            float4 v = *(const float4*)&Bp[(size_t)(ROWOFF + kb + krow) * NGATE +   \
                                           p * 256 + bn + c4];                      \
            *(float4*)&Bs[p][krow][c4] = v;                                         \
        }                                                                           \
        __syncthreads();                                                            \
        _Pragma("unroll")                                                           \
        for (int kk = 0; kk < FK; kk++) {                                           \
            float a[4], br[4], bz[4], bq[4];                                        \
            *(float4*)a  = *(const float4*)&As[kk][ty*4];                           \
            *(float4*)br = *(const float4*)&Bs[0][kk][tx*4];                        \
            *(float4*)bz = *(const float4*)&Bs[1][kk][tx*4];                        \
            *(float4*)bq = *(const float4*)&Bs[2][kk][tx*4];                        \
            _Pragma("unroll")                                                       \
            for (int i = 0; i < 4; i++) {                                           \
                _Pragma("unroll")                                                   \
                for (int j = 0; j < 4; j++) {                                       \
                    accR[i][j] += a[i] * br[j];                                     \
                    accZ[i][j] += a[i] * bz[j];                                     \
                    ACCN[i][j] += a[i] * bq[j];                                     \
                }                                                                   \
            }                                                                       \
        }                                                                           \
        __syncthreads();                                                            \
    }

    KHALF(agg, 0, accNi)
    KHALF(h, 256, accNh)
#undef KHALF

    float4 bir = *(const float4*)&b_ih[bn + tx*4];
    float4 biz = *(const float4*)&b_ih[256 + bn + tx*4];
    float4 bin = *(const float4*)&b_ih[512 + bn + tx*4];
    float4 bhr = *(const float4*)&b_hh[bn + tx*4];
    float4 bhz = *(const float4*)&b_hh[256 + bn + tx*4];
    float4 bhn = *(const float4*)&b_hh[512 + bn + tx*4];
    float cbr[4] = {bir.x+bhr.x, bir.y+bhr.y, bir.z+bhr.z, bir.w+bhr.w};
    float cbz[4] = {biz.x+bhz.x, biz.y+bhz.y, biz.z+bhz.z, biz.w+bhz.w};
    float cbi[4] = {bin.x, bin.y, bin.z, bin.w};
    float cbh[4] = {bhn.x, bhn.y, bhn.z, bhn.w};
    #pragma unroll
    for (int i = 0; i < 4; i++) {
        int n = bm + ty * 4 + i;
        if (n >= M) continue;
        float4 hp = *(const float4*)&h[(size_t)n * D + bn + tx*4];
        float hpv[4] = {hp.x, hp.y, hp.z, hp.w};
        float o[4];
        #pragma unroll
        for (int j = 0; j < 4; j++) {
            float r = sigm(accR[i][j] + cbr[j]);
            float z = sigm(accZ[i][j] + cbz[j]);
            float nn = tanhf(accNi[i][j] + cbi[j] + r * (accNh[i][j] + cbh[j]));
            o[j] = (1.f - z) * nn + z * hpv[j];
        }
        *(float4*)&hout[(size_t)n * D + bn + tx*4] = make_float4(o[0], o[1], o[2], o[3]);
    }
}

// ---------------- readout + softmax ----------------
__global__ __launch_bounds__(256) void readout_kernel(const float* __restrict__ h,
                                                      const float* __restrict__ w_ro,
                                                      const float* __restrict__ b_ro,
                                                      float* __restrict__ out, int M) {
    __shared__ float ws_[D * K_OUT];
    for (int i = threadIdx.x; i < D * K_OUT; i += 256) ws_[i] = w_ro[i];
    __syncthreads();
    int group = threadIdx.x >> 5;
    int col   = threadIdx.x & 31;
    int node  = blockIdx.x * 8 + group;
    if (node >= M) return;
    float acc = b_ro[col];
    const float* hrow = &h[(size_t)node * D];
    #pragma unroll 8
    for (int k = 0; k < D; k++) acc += hrow[k] * ws_[k * K_OUT + col];
    float mx = acc;
    #pragma unroll
    for (int off = 16; off > 0; off >>= 1) mx = fmaxf(mx, __shfl_xor(mx, off, 32));
    float e = __expf(acc - mx);
    float s = e;
    #pragma unroll
    for (int off = 16; off > 0; off >>= 1) s += __shfl_xor(s, off, 32);
    out[(size_t)node * K_OUT + col] = e / s;
}

extern "C" void kernel_launch(void* const* d_in, const int* in_sizes, int n_in,
                              void* d_out, int out_size, void* d_ws, size_t ws_size,
                              hipStream_t stream) {
    const float* x      = (const float*)d_in[0];
    const int*   ei     = (const int*)d_in[1];
    const float* ea     = (const float*)d_in[2];
    const float* weight = (const float*)d_in[3];
    const float* w_ih   = (const float*)d_in[4];
    const float* w_hh   = (const float*)d_in[5];
    const float* b_ih   = (const float*)d_in[6];
    const float* b_hh   = (const float*)d_in[7];
    const float* w_ro   = (const float*)d_in[8];
    const float* b_ro   = (const float*)d_in[9];
    float* out = (float*)d_out;

    int N = in_sizes[0];          // 50000
    int E = in_sizes[2];          // 800000
    const int* src = ei;
    const int* dst = ei + E;

    size_t ND = (size_t)N * D;
    float* hA    = (float*)d_ws;
    float* hB    = hA + ND;
    float* agg   = hB + ND;
    float* sx    = agg + ND;
    float* Bprep = sx + N;
    int*   cnt    = (int*)(Bprep + (size_t)L_LAYERS * 512 * NGATE);
    int*   rowptr = cnt + (N + 1);
    int*   cursor = rowptr + (N + 1);
    int*   esrc   = cursor + (N + 1);
    float* eval   = (float*)(esrc + E);

    // ---- CSR build ----
    hipMemsetAsync(cnt, 0, (N + 1) * sizeof(int), stream);
    hist_kernel<<<1024, 256, 0, stream>>>(dst, cnt, E);
    scan_kernel<<<1, 1024, 0, stream>>>(cnt, rowptr, cursor, N);
    reorder_kernel<<<1024, 256, 0, stream>>>(src, dst, ea, cursor, esrc, eval, E);

    // ---- weight precompute: Bprep[l] = [weight[l]@w_ih^T ; w_hh^T] ----
    prep_wih_kernel<<<dim3(4, 12, 4), 256, 0, stream>>>(weight, w_ih, Bprep);
    prep_whh_kernel<<<dim3(8, 24), 256, 0, stream>>>(w_hh, Bprep);

    // ---- layer 0 (rank-2) ----
    sgather_kernel<<<(N + 255) / 256, 256, 0, stream>>>(x, rowptr, esrc, eval, sx, N);
    layer0_kernel<<<(N + 3) / 4, 256, 0, stream>>>(x, sx, Bprep, b_ih, b_hh, hA, N);

    // ---- layers 1..3 ----
    float* hcur = hA;
    float* hnext = hB;
    dim3 gfused((N + FM - 1) / FM, D / FN);
    int gather_blocks = (N * 64 + 255) / 256;
    for (int l = 1; l < L_LAYERS; l++) {
        gather_kernel<<<gather_blocks, 256, 0, stream>>>(hcur, rowptr, esrc, eval, agg, N);
        fused_gru_kernel<<<gfused, 256, 0, stream>>>(agg, hcur,
                                                     Bprep + (size_t)l * 512 * NGATE,
                                                     b_ih, b_hh, hnext, N);
        float* t = hcur; hcur = hnext; hnext = t;
    }
    readout_kernel<<<(N + 7) / 8, 256, 0, stream>>>(hcur, w_ro, b_ro, out, N);
}

// Round 5
// 1968.062 us; speedup vs baseline: 7.3411x; 1.6413x over previous
//
#include <hip/hip_runtime.h>

#define D 256
#define K_OUT 32
#define L_LAYERS 4
#define NPAD 50048

typedef __attribute__((ext_vector_type(8))) short bf16x8;
typedef __attribute__((ext_vector_type(4))) float f32x4;
typedef __attribute__((address_space(3))) unsigned int lds_u32;
typedef const __attribute__((address_space(1))) unsigned int glb_u32;

__device__ __forceinline__ float sigm(float v) { return 1.f / (1.f + __expf(-v)); }
__device__ __forceinline__ unsigned short f2bf(float f) {
    unsigned u = __float_as_uint(f);
    u = u + 0x7fffu + ((u >> 16) & 1u);
    return (unsigned short)(u >> 16);
}
__device__ __forceinline__ float bf2f(unsigned short s) {
    return __uint_as_float(((unsigned)s) << 16);
}
__device__ __forceinline__ void gload16(const unsigned short* g, unsigned short* l) {
    __builtin_amdgcn_global_load_lds((glb_u32*)g, (lds_u32*)l, 16, 0, 0);
}

// ---------------- CSR build ----------------
__global__ __launch_bounds__(256) void hist_kernel(const int* __restrict__ dst,
                                                   int* __restrict__ cnt, int E) {
    int idx = blockIdx.x * blockDim.x + threadIdx.x;
    for (int e = idx; e < E; e += gridDim.x * blockDim.x)
        atomicAdd(&cnt[dst[e]], 1);
}

__global__ __launch_bounds__(1024) void scan_kernel(const int* __restrict__ cnt,
                                                    int* __restrict__ rowptr,
                                                    int* __restrict__ cursor, int n) {
    __shared__ int sdata[1024];
    int t = threadIdx.x;
    int chunk = (n + 1023) / 1024;
    int start = t * chunk;
    int end = start + chunk; if (end > n) end = n;
    int s = 0;
    for (int i = start; i < end; i++) s += cnt[i];
    sdata[t] = s;
    __syncthreads();
    for (int off = 1; off < 1024; off <<= 1) {
        int v = (t >= off) ? sdata[t - off] : 0;
        __syncthreads();
        sdata[t] += v;
        __syncthreads();
    }
    int base = sdata[t] - s;
    for (int i = start; i < end; i++) {
        rowptr[i] = base;
        cursor[i] = base;
        base += cnt[i];
    }
    if (end == n && start <= n) rowptr[n] = base;
}

__global__ __launch_bounds__(256) void reorder_kernel(const int* __restrict__ src,
                                                      const int* __restrict__ dst,
                                                      const float* __restrict__ ea,
                                                      int* __restrict__ cursor,
                                                      int* __restrict__ esrc,
                                                      float* __restrict__ eval, int E) {
    int idx = blockIdx.x * blockDim.x + threadIdx.x;
    for (int e = idx; e < E; e += gridDim.x * blockDim.x) {
        int slot = atomicAdd(&cursor[dst[e]], 1);
        esrc[slot] = src[e];
        eval[slot] = ea[e];
    }
}

// ---------------- P[l][k][c3] = (weight[l] @ w_ih^T)[k][c3], 256x768 per layer ----------------
__global__ __launch_bounds__(256) void prep_wih_kernel(const float* __restrict__ weight,
                                                       const float* __restrict__ w_ih,
                                                       float* __restrict__ P) {
    int l = blockIdx.z;
    const float* A = weight + (size_t)l * D * D;
    float* Cdst = P + (size_t)l * 256 * 768;
    __shared__ float As[32][64 + 4];
    __shared__ float Bs[32][64 + 4];
    int tid = threadIdx.x;
    int tx = tid & 15, ty = tid >> 4;
    int bk = blockIdx.x * 64;
    int bn = blockIdx.y * 64;
    float acc[4][4] = {};
    for (int jb = 0; jb < D; jb += 32) {
        #pragma unroll
        for (int i = 0; i < 2; i++) {
            int lin = tid + i * 256;
            int row = lin >> 3;
            int c4 = (lin & 7) << 2;
            float4 v = *(const float4*)&A[(size_t)(bk + row) * D + jb + c4];
            As[c4+0][row]=v.x; As[c4+1][row]=v.y; As[c4+2][row]=v.z; As[c4+3][row]=v.w;
            float4 w = *(const float4*)&w_ih[(size_t)(bn + row) * D + jb + c4];
            Bs[c4+0][row]=w.x; Bs[c4+1][row]=w.y; Bs[c4+2][row]=w.z; Bs[c4+3][row]=w.w;
        }
        __syncthreads();
        #pragma unroll
        for (int jj = 0; jj < 32; jj++) {
            float a[4], b[4];
            *(float4*)a = *(const float4*)&As[jj][ty*4];
            *(float4*)b = *(const float4*)&Bs[jj][tx*4];
            #pragma unroll
            for (int i = 0; i < 4; i++)
                #pragma unroll
                for (int j = 0; j < 4; j++)
                    acc[i][j] += a[i] * b[j];
        }
        __syncthreads();
    }
    #pragma unroll
    for (int i = 0; i < 4; i++)
        *(float4*)&Cdst[(size_t)(bk + ty*4 + i) * 768 + bn + tx*4] =
            make_float4(acc[i][0], acc[i][1], acc[i][2], acc[i][3]);
}

// ---------------- BT2[l][c][k2] bf16: c=g*256+d (g: r,z,ni,nh), k2<512 hi, >=512 lo ----------------
__global__ __launch_bounds__(256) void pack_bt2_kernel(const float* __restrict__ P,
                                                       const float* __restrict__ w_hh,
                                                       unsigned short* __restrict__ BT2) {
    long long idx = (long long)blockIdx.x * 256 + threadIdx.x;   // 4M total
    int l = (int)(idx >> 20);
    int rem = (int)(idx & 1048575);
    int c = rem >> 10;
    int k2 = rem & 1023;
    int g = c >> 8, d = c & 255;
    int k = k2 & 511;
    float val;
    if (k < 256) {
        val = (g == 0) ? P[(size_t)l * 196608 + (size_t)k * 768 + d]
            : (g == 1) ? P[(size_t)l * 196608 + (size_t)k * 768 + 256 + d]
            : (g == 2) ? P[(size_t)l * 196608 + (size_t)k * 768 + 512 + d]
            : 0.f;
    } else {
        int kk = k - 256;
        val = (g == 0) ? w_hh[(size_t)d * D + kk]
            : (g == 1) ? w_hh[(size_t)(256 + d) * D + kk]
            : (g == 3) ? w_hh[(size_t)(512 + d) * D + kk]
            : 0.f;
    }
    unsigned short hi = f2bf(val);
    BT2[idx] = (k2 < 512) ? hi : f2bf(val - bf2f(hi));
}

// ---------------- scalar gather: sx[n] = sum ea * x[src] ----------------
__global__ __launch_bounds__(256) void sgather_kernel(const float* __restrict__ x,
                                                      const int* __restrict__ rowptr,
                                                      const int* __restrict__ esrc,
                                                      const float* __restrict__ eval,
                                                      float* __restrict__ sx, int n) {
    int node = blockIdx.x * blockDim.x + threadIdx.x;
    if (node >= n) return;
    float s = 0.f;
    int end = rowptr[node + 1];
    for (int e = rowptr[node]; e < end; e++) s += eval[e] * x[esrc[e]];
    sx[node] = s;
}

// ---------------- layer 0: rank-2 + GRU epilogue, writes h ----------------
__global__ __launch_bounds__(256) void layer0_kernel(const float* __restrict__ x,
                                                     const float* __restrict__ sx,
                                                     const float* __restrict__ P0,
                                                     const float* __restrict__ w_hh,
                                                     const float* __restrict__ b_ih,
                                                     const float* __restrict__ b_hh,
                                                     float* __restrict__ hout, int M) {
    int node = blockIdx.x * 4 + (threadIdx.x >> 6);
    if (node >= M) return;
    int d0 = (threadIdx.x & 63) * 4;
    float sxn = sx[node], xn = x[node];
    float4 r0 = *(const float4*)&P0[d0];
    float4 z0 = *(const float4*)&P0[256 + d0];
    float4 n0 = *(const float4*)&P0[512 + d0];
    float r1[4], z1[4], n1[4];
    #pragma unroll
    for (int j = 0; j < 4; j++) {
        r1[j] = w_hh[(size_t)(d0 + j) * D];
        z1[j] = w_hh[(size_t)(256 + d0 + j) * D];
        n1[j] = w_hh[(size_t)(512 + d0 + j) * D];
    }
    float4 bir = *(const float4*)&b_ih[d0];
    float4 biz = *(const float4*)&b_ih[256 + d0];
    float4 bin = *(const float4*)&b_ih[512 + d0];
    float4 bhr = *(const float4*)&b_hh[d0];
    float4 bhz = *(const float4*)&b_hh[256 + d0];
    float4 bhn = *(const float4*)&b_hh[512 + d0];
    float rr[4] = {sxn*r0.x + xn*r1[0] + bir.x + bhr.x, sxn*r0.y + xn*r1[1] + bir.y + bhr.y,
                   sxn*r0.z + xn*r1[2] + bir.z + bhr.z, sxn*r0.w + xn*r1[3] + bir.w + bhr.w};
    float zz[4] = {sxn*z0.x + xn*z1[0] + biz.x + bhz.x, sxn*z0.y + xn*z1[1] + biz.y + bhz.y,
                   sxn*z0.z + xn*z1[2] + biz.z + bhz.z, sxn*z0.w + xn*z1[3] + biz.w + bhz.w};
    float ni[4] = {sxn*n0.x + bin.x, sxn*n0.y + bin.y, sxn*n0.z + bin.z, sxn*n0.w + bin.w};
    float nh[4] = {xn*n1[0] + bhn.x, xn*n1[1] + bhn.y, xn*n1[2] + bhn.z, xn*n1[3] + bhn.w};
    float o[4];
    #pragma unroll
    for (int j = 0; j < 4; j++) {
        float r = sigm(rr[j]);
        float z = sigm(zz[j]);
        float nn = tanhf(ni[j] + r * nh[j]);
        float hp = (d0 + j == 0) ? xn : 0.f;
        o[j] = (1.f - z) * nn + z * hp;
    }
    *(float4*)&hout[(size_t)node * D + d0] = make_float4(o[0], o[1], o[2], o[3]);
}

// ---------------- h -> A2 h-cols (hi at 256+d, lo at 768+d) ----------------
__global__ __launch_bounds__(256) void h2bf_kernel(const float* __restrict__ h,
                                                   unsigned short* __restrict__ A2, int n) {
    int idx = blockIdx.x * 256 + threadIdx.x;
    if (idx >= n * 64) return;
    int node = idx >> 6, q = (idx & 63) * 4;
    float4 v = *(const float4*)&h[(size_t)node * D + q];
    ushort4 hi = make_ushort4(f2bf(v.x), f2bf(v.y), f2bf(v.z), f2bf(v.w));
    ushort4 lo = make_ushort4(f2bf(v.x - bf2f(hi.x)), f2bf(v.y - bf2f(hi.y)),
                              f2bf(v.z - bf2f(hi.z)), f2bf(v.w - bf2f(hi.w)));
    *(ushort4*)&A2[(size_t)node * 1024 + 256 + q] = hi;
    *(ushort4*)&A2[(size_t)node * 1024 + 768 + q] = lo;
}

// ---------------- gather: agg -> A2 agg-cols (hi at d, lo at 512+d) ----------------
__global__ __launch_bounds__(256) void gather_bf_kernel(const float* __restrict__ h,
                                                        const int* __restrict__ rowptr,
                                                        const int* __restrict__ esrc,
                                                        const float* __restrict__ eval,
                                                        unsigned short* __restrict__ A2, int n) {
    int node = (blockIdx.x * 256 + threadIdx.x) >> 6;
    int lane = threadIdx.x & 63;
    if (node >= n) return;
    int beg = rowptr[node], end = rowptr[node + 1];
    float4 acc = make_float4(0.f, 0.f, 0.f, 0.f);
    for (int e = beg; e < end; e++) {
        int s = esrc[e];
        float a = eval[e];
        float4 v = *(const float4*)&h[(size_t)s * D + lane * 4];
        acc.x += a * v.x; acc.y += a * v.y; acc.z += a * v.z; acc.w += a * v.w;
    }
    ushort4 hi = make_ushort4(f2bf(acc.x), f2bf(acc.y), f2bf(acc.z), f2bf(acc.w));
    ushort4 lo = make_ushort4(f2bf(acc.x - bf2f(hi.x)), f2bf(acc.y - bf2f(hi.y)),
                              f2bf(acc.z - bf2f(hi.z)), f2bf(acc.w - bf2f(hi.w)));
    *(ushort4*)&A2[(size_t)node * 1024 + lane * 4] = hi;
    *(ushort4*)&A2[(size_t)node * 1024 + 512 + lane * 4] = lo;
}

// ---------------- MFMA GRU: [A2](Nx1536 eff) @ BT2^T -> gates, fused epilogue ----------------
__global__ __launch_bounds__(256) void gru_mfma_kernel(const unsigned short* __restrict__ A2,
                                                       const unsigned short* __restrict__ BT2,
                                                       const float* __restrict__ b_ih,
                                                       const float* __restrict__ b_hh,
                                                       float* __restrict__ h, int M) {
    __shared__ unsigned short Asm[2][8 * 512];
    __shared__ unsigned short Bsm[2][8 * 512];
    int tid = threadIdx.x;
    int lane = tid & 63;
    int wid = tid >> 6;
    int wr = wid >> 1, wc = wid & 1;
    int bm = blockIdx.x * 128;
    int bnd = blockIdx.y * 32;

    // fragment-linear staging addresses (global side varies per lane; LDS dest is wave-uniform base)
    size_t aoff0 = (size_t)(bm + wid * 32 + (lane & 15)) * 1024 + ((lane >> 4) << 3);
    size_t aoff1 = aoff0 + (size_t)16 * 1024;
    size_t boff0 = (size_t)(wid * 256 + bnd + (lane & 15)) * 1024 + ((lane >> 4) << 3);
    size_t boff1 = boff0 + (size_t)16 * 1024;

    f32x4 acc[4][4];
    #pragma unroll
    for (int i = 0; i < 4; i++)
        #pragma unroll
        for (int j = 0; j < 4; j++)
            acc[i][j] = (f32x4){0.f, 0.f, 0.f, 0.f};

    gload16(A2 + aoff0, &Asm[0][(2 * wid) * 512]);
    gload16(A2 + aoff1, &Asm[0][(2 * wid + 1) * 512]);
    gload16(BT2 + boff0, &Bsm[0][(2 * wid) * 512]);
    gload16(BT2 + boff1, &Bsm[0][(2 * wid + 1) * 512]);
    __syncthreads();

    int cur = 0;
    for (int t = 0; t < 48; t++) {
        if (t < 47) {
            int kb = (t + 1) << 5;
            int ac = (kb < 1024) ? kb : kb - 1024;   // A2: [X_hi(512)|X_lo(512)], 3rd chunk re-reads hi
            int bc = (kb < 512) ? kb : kb - 512;     // BT2: [B_hi(512)|B_lo(512)], chunk2 re-reads hi
            int nb = cur ^ 1;
            gload16(A2 + aoff0 + ac, &Asm[nb][(2 * wid) * 512]);
            gload16(A2 + aoff1 + ac, &Asm[nb][(2 * wid + 1) * 512]);
            gload16(BT2 + boff0 + bc, &Bsm[nb][(2 * wid) * 512]);
            gload16(BT2 + boff1 + bc, &Bsm[nb][(2 * wid + 1) * 512]);
        }
        bf16x8 a[4], b[4];
        #pragma unroll
        for (int m = 0; m < 4; m++)
            a[m] = *(const bf16x8*)&Asm[cur][(wr * 4 + m) * 512 + lane * 8];
        #pragma unroll
        for (int g = 0; g < 4; g++)
            b[g] = *(const bf16x8*)&Bsm[cur][(g * 2 + wc) * 512 + lane * 8];
        #pragma unroll
        for (int m = 0; m < 4; m++)
            #pragma unroll
            for (int g = 0; g < 4; g++)
                acc[m][g] = __builtin_amdgcn_mfma_f32_16x16x32_bf16(a[m], b[g], acc[m][g], 0, 0, 0);
        __syncthreads();
        cur ^= 1;
    }

    // epilogue: C layout col=lane&15, row=(lane>>4)*4+reg  [m89-verified]
    int d = bnd + wc * 16 + (lane & 15);
    float cbr = b_ih[d] + b_hh[d];
    float cbz = b_ih[D + d] + b_hh[D + d];
    float bin = b_ih[2 * D + d];
    float bhn = b_hh[2 * D + d];
    int rbase = bm + wr * 64 + (lane >> 4) * 4;
    #pragma unroll
    for (int m = 0; m < 4; m++) {
        #pragma unroll
        for (int q = 0; q < 4; q++) {
            int row = rbase + m * 16 + q;
            if (row < M) {
                float r = sigm(acc[m][0][q] + cbr);
                float z = sigm(acc[m][1][q] + cbz);
                float nn = tanhf(acc[m][2][q] + bin + r * (acc[m][3][q] + bhn));
                float* hp = &h[(size_t)row * D + d];
                float hv = *hp;
                *hp = (1.f - z) * nn + z * hv;
            }
        }
    }
}

// ---------------- readout + softmax ----------------
__global__ __launch_bounds__(256) void readout_kernel(const float* __restrict__ h,
                                                      const float* __restrict__ w_ro,
                                                      const float* __restrict__ b_ro,
                                                      float* __restrict__ out, int M) {
    __shared__ float ws_[D * K_OUT];
    for (int i = threadIdx.x; i < D * K_OUT; i += 256) ws_[i] = w_ro[i];
    __syncthreads();
    int group = threadIdx.x >> 5;
    int col   = threadIdx.x & 31;
    int node  = blockIdx.x * 8 + group;
    if (node >= M) return;
    float acc = b_ro[col];
    const float* hrow = &h[(size_t)node * D];
    #pragma unroll 8
    for (int k = 0; k < D; k++) acc += hrow[k] * ws_[k * K_OUT + col];
    float mx = acc;
    #pragma unroll
    for (int off = 16; off > 0; off >>= 1) mx = fmaxf(mx, __shfl_xor(mx, off, 32));
    float e = __expf(acc - mx);
    float s = e;
    #pragma unroll
    for (int off = 16; off > 0; off >>= 1) s += __shfl_xor(s, off, 32);
    out[(size_t)node * K_OUT + col] = e / s;
}

extern "C" void kernel_launch(void* const* d_in, const int* in_sizes, int n_in,
                              void* d_out, int out_size, void* d_ws, size_t ws_size,
                              hipStream_t stream) {
    const float* x      = (const float*)d_in[0];
    const int*   ei     = (const int*)d_in[1];
    const float* ea     = (const float*)d_in[2];
    const float* weight = (const float*)d_in[3];
    const float* w_ih   = (const float*)d_in[4];
    const float* w_hh   = (const float*)d_in[5];
    const float* b_ih   = (const float*)d_in[6];
    const float* b_hh   = (const float*)d_in[7];
    const float* w_ro   = (const float*)d_in[8];
    const float* b_ro   = (const float*)d_in[9];
    float* out = (float*)d_out;

    int N = in_sizes[0];          // 50000
    int E = in_sizes[2];          // 800000
    const int* src = ei;
    const int* dst = ei + E;

    size_t ND = (size_t)N * D;
    float* h = (float*)d_ws;
    unsigned short* A2 = (unsigned short*)(h + ND);                      // NPAD x 1024 bf16
    float* P = (float*)(A2 + (size_t)NPAD * 1024);                       // 4 x 256 x 768
    unsigned short* BT2 = (unsigned short*)(P + (size_t)L_LAYERS * 256 * 768); // 4 x 1024 x 1024
    float* sx = (float*)(BT2 + (size_t)L_LAYERS * 1024 * 1024);
    int* cnt = (int*)(sx + N);
    int* rowptr = cnt + (N + 1);
    int* cursor = rowptr + (N + 1);
    int* esrc = cursor + (N + 1);
    float* eval = (float*)(esrc + E);

    // ---- CSR build ----
    hipMemsetAsync(cnt, 0, (N + 1) * sizeof(int), stream);
    hist_kernel<<<1024, 256, 0, stream>>>(dst, cnt, E);
    scan_kernel<<<1, 1024, 0, stream>>>(cnt, rowptr, cursor, N);
    reorder_kernel<<<1024, 256, 0, stream>>>(src, dst, ea, cursor, esrc, eval, E);

    // ---- weight precompute ----
    prep_wih_kernel<<<dim3(4, 12, 4), 256, 0, stream>>>(weight, w_ih, P);
    pack_bt2_kernel<<<16384, 256, 0, stream>>>(P, w_hh, BT2);

    // ---- layer 0 (rank-2) ----
    sgather_kernel<<<(N + 255) / 256, 256, 0, stream>>>(x, rowptr, esrc, eval, sx, N);
    layer0_kernel<<<(N + 3) / 4, 256, 0, stream>>>(x, sx, P, w_hh, b_ih, b_hh, h, N);
    h2bf_kernel<<<(N * 64 + 255) / 256, 256, 0, stream>>>(h, A2, N);

    // ---- layers 1..3 ----
    dim3 gm(NPAD / 128, 8);
    int gather_blocks = (N * 64 + 255) / 256;
    for (int l = 1; l < L_LAYERS; l++) {
        gather_bf_kernel<<<gather_blocks, 256, 0, stream>>>(h, rowptr, esrc, eval, A2, N);
        gru_mfma_kernel<<<gm, 256, 0, stream>>>(A2, BT2 + (size_t)l * 1024 * 1024,
                                                b_ih, b_hh, h, N);
        if (l < L_LAYERS - 1)
            h2bf_kernel<<<(N * 64 + 255) / 256, 256, 0, stream>>>(h, A2, N);
    }
    readout_kernel<<<(N + 7) / 8, 256, 0, stream>>>(h, w_ro, b_ro, out, N);
}

// Round 7
// 1605.075 us; speedup vs baseline: 9.0012x; 1.2261x over previous
//
#include <hip/hip_runtime.h>

#define D 256
#define K_OUT 32
#define L_LAYERS 4
#define NPAD 50048

typedef __attribute__((ext_vector_type(8))) short bf16x8;
typedef __attribute__((ext_vector_type(4))) float f32x4;
typedef __attribute__((address_space(3))) unsigned int lds_u32;
typedef const __attribute__((address_space(1))) unsigned int glb_u32;

__device__ __forceinline__ float sigm(float v) { return 1.f / (1.f + __expf(-v)); }
__device__ __forceinline__ unsigned short f2bf(float f) {
    unsigned u = __float_as_uint(f);
    u = u + 0x7fffu + ((u >> 16) & 1u);
    return (unsigned short)(u >> 16);
}
__device__ __forceinline__ float bf2f(unsigned short s) {
    return __uint_as_float(((unsigned)s) << 16);
}
__device__ __forceinline__ void gload16(const unsigned short* g, unsigned short* l) {
    __builtin_amdgcn_global_load_lds((glb_u32*)g, (lds_u32*)l, 16, 0, 0);
}

// ---------------- CSR build ----------------
__global__ __launch_bounds__(256) void hist_kernel(const int* __restrict__ dst,
                                                   int* __restrict__ cnt, int E) {
    int idx = blockIdx.x * blockDim.x + threadIdx.x;
    for (int e = idx; e < E; e += gridDim.x * blockDim.x)
        atomicAdd(&cnt[dst[e]], 1);
}

__global__ __launch_bounds__(1024) void scan_kernel(const int* __restrict__ cnt,
                                                    int* __restrict__ rowptr,
                                                    int* __restrict__ cursor, int n) {
    __shared__ int sdata[1024];
    int t = threadIdx.x;
    int chunk = (n + 1023) / 1024;
    int start = t * chunk;
    int end = start + chunk; if (end > n) end = n;
    int s = 0;
    for (int i = start; i < end; i++) s += cnt[i];
    sdata[t] = s;
    __syncthreads();
    for (int off = 1; off < 1024; off <<= 1) {
        int v = (t >= off) ? sdata[t - off] : 0;
        __syncthreads();
        sdata[t] += v;
        __syncthreads();
    }
    int base = sdata[t] - s;
    for (int i = start; i < end; i++) {
        rowptr[i] = base;
        cursor[i] = base;
        base += cnt[i];
    }
    if (end == n && start <= n) rowptr[n] = base;
}

__global__ __launch_bounds__(256) void reorder_kernel(const int* __restrict__ src,
                                                      const int* __restrict__ dst,
                                                      const float* __restrict__ ea,
                                                      int* __restrict__ cursor,
                                                      int* __restrict__ esrc,
                                                      float* __restrict__ eval, int E) {
    int idx = blockIdx.x * blockDim.x + threadIdx.x;
    for (int e = idx; e < E; e += gridDim.x * blockDim.x) {
        int slot = atomicAdd(&cursor[dst[e]], 1);
        esrc[slot] = src[e];
        eval[slot] = ea[e];
    }
}

// ---------------- P[l][k][c3] = (weight[l] @ w_ih^T)[k][c3], 256x768 per layer ----------------
__global__ __launch_bounds__(256) void prep_wih_kernel(const float* __restrict__ weight,
                                                       const float* __restrict__ w_ih,
                                                       float* __restrict__ P) {
    int l = blockIdx.z;
    const float* A = weight + (size_t)l * D * D;
    float* Cdst = P + (size_t)l * 256 * 768;
    __shared__ float As[32][64 + 4];
    __shared__ float Bs[32][64 + 4];
    int tid = threadIdx.x;
    int tx = tid & 15, ty = tid >> 4;
    int bk = blockIdx.x * 64;
    int bn = blockIdx.y * 64;
    float acc[4][4] = {};
    for (int jb = 0; jb < D; jb += 32) {
        #pragma unroll
        for (int i = 0; i < 2; i++) {
            int lin = tid + i * 256;
            int row = lin >> 3;
            int c4 = (lin & 7) << 2;
            float4 v = *(const float4*)&A[(size_t)(bk + row) * D + jb + c4];
            As[c4+0][row]=v.x; As[c4+1][row]=v.y; As[c4+2][row]=v.z; As[c4+3][row]=v.w;
            float4 w = *(const float4*)&w_ih[(size_t)(bn + row) * D + jb + c4];
            Bs[c4+0][row]=w.x; Bs[c4+1][row]=w.y; Bs[c4+2][row]=w.z; Bs[c4+3][row]=w.w;
        }
        __syncthreads();
        #pragma unroll
        for (int jj = 0; jj < 32; jj++) {
            float a[4], b[4];
            *(float4*)a = *(const float4*)&As[jj][ty*4];
            *(float4*)b = *(const float4*)&Bs[jj][tx*4];
            #pragma unroll
            for (int i = 0; i < 4; i++)
                #pragma unroll
                for (int j = 0; j < 4; j++)
                    acc[i][j] += a[i] * b[j];
        }
        __syncthreads();
    }
    #pragma unroll
    for (int i = 0; i < 4; i++)
        *(float4*)&Cdst[(size_t)(bk + ty*4 + i) * 768 + bn + tx*4] =
            make_float4(acc[i][0], acc[i][1], acc[i][2], acc[i][3]);
}

// ---------------- BT2[l][c][k2] bf16: c=g*256+d (g: r,z,ni,nh), k2<512 hi, >=512 lo ----------------
__global__ __launch_bounds__(256) void pack_bt2_kernel(const float* __restrict__ P,
                                                       const float* __restrict__ w_hh,
                                                       unsigned short* __restrict__ BT2) {
    long long idx = (long long)blockIdx.x * 256 + threadIdx.x;   // 4M total
    int l = (int)(idx >> 20);
    int rem = (int)(idx & 1048575);
    int c = rem >> 10;
    int k2 = rem & 1023;
    int g = c >> 8, d = c & 255;
    int k = k2 & 511;
    float val;
    if (k < 256) {
        val = (g == 0) ? P[(size_t)l * 196608 + (size_t)k * 768 + d]
            : (g == 1) ? P[(size_t)l * 196608 + (size_t)k * 768 + 256 + d]
            : (g == 2) ? P[(size_t)l * 196608 + (size_t)k * 768 + 512 + d]
            : 0.f;
    } else {
        int kk = k - 256;
        val = (g == 0) ? w_hh[(size_t)d * D + kk]
            : (g == 1) ? w_hh[(size_t)(256 + d) * D + kk]
            : (g == 3) ? w_hh[(size_t)(512 + d) * D + kk]
            : 0.f;
    }
    unsigned short hi = f2bf(val);
    BT2[idx] = (k2 < 512) ? hi : f2bf(val - bf2f(hi));
}

// ---------------- scalar gather: sx[n] = sum ea * x[src] ----------------
__global__ __launch_bounds__(256) void sgather_kernel(const float* __restrict__ x,
                                                      const int* __restrict__ rowptr,
                                                      const int* __restrict__ esrc,
                                                      const float* __restrict__ eval,
                                                      float* __restrict__ sx, int n) {
    int node = blockIdx.x * blockDim.x + threadIdx.x;
    if (node >= n) return;
    float s = 0.f;
    int end = rowptr[node + 1];
    for (int e = rowptr[node]; e < end; e++) s += eval[e] * x[esrc[e]];
    sx[node] = s;
}

// ---------------- layer 0: rank-2 + GRU epilogue, writes h ----------------
__global__ __launch_bounds__(256) void layer0_kernel(const float* __restrict__ x,
                                                     const float* __restrict__ sx,
                                                     const float* __restrict__ P0,
                                                     const float* __restrict__ w_hh,
                                                     const float* __restrict__ b_ih,
                                                     const float* __restrict__ b_hh,
                                                     float* __restrict__ hout, int M) {
    int node = blockIdx.x * 4 + (threadIdx.x >> 6);
    if (node >= M) return;
    int d0 = (threadIdx.x & 63) * 4;
    float sxn = sx[node], xn = x[node];
    float4 r0 = *(const float4*)&P0[d0];
    float4 z0 = *(const float4*)&P0[256 + d0];
    float4 n0 = *(const float4*)&P0[512 + d0];
    float r1[4], z1[4], n1[4];
    #pragma unroll
    for (int j = 0; j < 4; j++) {
        r1[j] = w_hh[(size_t)(d0 + j) * D];
        z1[j] = w_hh[(size_t)(256 + d0 + j) * D];
        n1[j] = w_hh[(size_t)(512 + d0 + j) * D];
    }
    float4 bir = *(const float4*)&b_ih[d0];
    float4 biz = *(const float4*)&b_ih[256 + d0];
    float4 bin = *(const float4*)&b_ih[512 + d0];
    float4 bhr = *(const float4*)&b_hh[d0];
    float4 bhz = *(const float4*)&b_hh[256 + d0];
    float4 bhn = *(const float4*)&b_hh[512 + d0];
    float rr[4] = {sxn*r0.x + xn*r1[0] + bir.x + bhr.x, sxn*r0.y + xn*r1[1] + bir.y + bhr.y,
                   sxn*r0.z + xn*r1[2] + bir.z + bhr.z, sxn*r0.w + xn*r1[3] + bir.w + bhr.w};
    float zz[4] = {sxn*z0.x + xn*z1[0] + biz.x + bhz.x, sxn*z0.y + xn*z1[1] + biz.y + bhz.y,
                   sxn*z0.z + xn*z1[2] + biz.z + bhz.z, sxn*z0.w + xn*z1[3] + biz.w + bhz.w};
    float ni[4] = {sxn*n0.x + bin.x, sxn*n0.y + bin.y, sxn*n0.z + bin.z, sxn*n0.w + bin.w};
    float nh[4] = {xn*n1[0] + bhn.x, xn*n1[1] + bhn.y, xn*n1[2] + bhn.z, xn*n1[3] + bhn.w};
    float o[4];
    #pragma unroll
    for (int j = 0; j < 4; j++) {
        float r = sigm(rr[j]);
        float z = sigm(zz[j]);
        float nn = tanhf(ni[j] + r * nh[j]);
        float hp = (d0 + j == 0) ? xn : 0.f;
        o[j] = (1.f - z) * nn + z * hp;
    }
    *(float4*)&hout[(size_t)node * D + d0] = make_float4(o[0], o[1], o[2], o[3]);
}

// ---------------- gather + fused h2bf: runs after gru fully completes (kernel boundary) ----
// writes A2 agg-cols (hi at d, lo at 512+d) AND A2 h-cols (hi at 256+d, lo at 768+d)
__global__ __launch_bounds__(256) void gather_bf_kernel(const float* __restrict__ h,
                                                        const int* __restrict__ rowptr,
                                                        const int* __restrict__ esrc,
                                                        const float* __restrict__ eval,
                                                        unsigned short* __restrict__ A2, int n) {
    int node = (blockIdx.x * 256 + threadIdx.x) >> 6;
    int lane = threadIdx.x & 63;
    if (node >= n) return;
    int beg = rowptr[node], end = rowptr[node + 1];
    float4 acc = make_float4(0.f, 0.f, 0.f, 0.f);
    for (int e = beg; e < end; e++) {
        int s = esrc[e];
        float a = eval[e];
        float4 v = *(const float4*)&h[(size_t)s * D + lane * 4];
        acc.x += a * v.x; acc.y += a * v.y; acc.z += a * v.z; acc.w += a * v.w;
    }
    ushort4 hi = make_ushort4(f2bf(acc.x), f2bf(acc.y), f2bf(acc.z), f2bf(acc.w));
    ushort4 lo = make_ushort4(f2bf(acc.x - bf2f(hi.x)), f2bf(acc.y - bf2f(hi.y)),
                              f2bf(acc.z - bf2f(hi.z)), f2bf(acc.w - bf2f(hi.w)));
    *(ushort4*)&A2[(size_t)node * 1024 + lane * 4] = hi;
    *(ushort4*)&A2[(size_t)node * 1024 + 512 + lane * 4] = lo;
    // own-row h -> bf16 hi/lo (h is stable here; gru of previous layer has completed)
    float4 hv = *(const float4*)&h[(size_t)node * D + lane * 4];
    ushort4 hh = make_ushort4(f2bf(hv.x), f2bf(hv.y), f2bf(hv.z), f2bf(hv.w));
    ushort4 hl = make_ushort4(f2bf(hv.x - bf2f(hh.x)), f2bf(hv.y - bf2f(hh.y)),
                              f2bf(hv.z - bf2f(hh.z)), f2bf(hv.w - bf2f(hh.w)));
    *(ushort4*)&A2[(size_t)node * 1024 + 256 + lane * 4] = hh;
    *(ushort4*)&A2[(size_t)node * 1024 + 768 + lane * 4] = hl;
}

// ---------------- MFMA GRU v2: 128 rows x 64 d per block, 16 K-iters x 3 products ----------------
// LDS: 48 fragment blocks of 1 KB: [0,8)=A_hi, [8,16)=A_lo, [16,32)=B_hi, [32,48)=B_lo
// epilogue writes ONLY fp32 h (each (row,d) owned by exactly one thread grid-wide)
__global__ __launch_bounds__(256, 2) void gru_mfma_kernel(const unsigned short* __restrict__ A2,
                                                          const unsigned short* __restrict__ BT2,
                                                          const float* __restrict__ b_ih,
                                                          const float* __restrict__ b_hh,
                                                          float* __restrict__ h, int M) {
    __shared__ unsigned short sm[24576];   // 48 KB
    int tid = threadIdx.x;
    int lane = tid & 63;
    int wid = tid >> 6;
    int wr = wid >> 1, wc = wid & 1;
    int bm = blockIdx.x * 128;
    int bnd = blockIdx.y * 64;

    // precompute the 12 staging offsets this wave owns (frag f = wid*12 + ff)
    unsigned goff[12];
    bool gisA[12];
    #pragma unroll
    for (int ff = 0; ff < 12; ff++) {
        int f = wid * 12 + ff;
        unsigned r, cb;
        bool isA = (f < 16);
        if (f < 8)       { r = bm + f * 16 + (lane & 15);       cb = 0; }
        else if (f < 16) { r = bm + (f - 8) * 16 + (lane & 15); cb = 512; }
        else if (f < 32) { int q = f - 16; r = (q >> 2) * 256 + bnd + (q & 3) * 16 + (lane & 15); cb = 0; }
        else             { int q = f - 32; r = (q >> 2) * 256 + bnd + (q & 3) * 16 + (lane & 15); cb = 512; }
        goff[ff] = r * 1024u + cb + ((lane >> 4) << 3);
        gisA[ff] = isA;
    }

    f32x4 acc[4][8];
    #pragma unroll
    for (int i = 0; i < 4; i++)
        #pragma unroll
        for (int j = 0; j < 8; j++)
            acc[i][j] = (f32x4){0.f, 0.f, 0.f, 0.f};

    for (int c = 0; c < 16; c++) {
        #pragma unroll
        for (int ff = 0; ff < 12; ff++) {
            const unsigned short* g = (gisA[ff] ? A2 : BT2) + goff[ff] + c * 32;
            gload16(g, &sm[(wid * 12 + ff) * 512]);
        }
        __syncthreads();
        bf16x8 ah[4], al[4], bh[8], bl[8];
        #pragma unroll
        for (int m = 0; m < 4; m++) {
            ah[m] = *(const bf16x8*)&sm[(wr * 4 + m) * 512 + lane * 8];
            al[m] = *(const bf16x8*)&sm[(8 + wr * 4 + m) * 512 + lane * 8];
        }
        #pragma unroll
        for (int n = 0; n < 8; n++) {
            int fb = (n >> 1) * 4 + wc * 2 + (n & 1);
            bh[n] = *(const bf16x8*)&sm[(16 + fb) * 512 + lane * 8];
            bl[n] = *(const bf16x8*)&sm[(32 + fb) * 512 + lane * 8];
        }
        #pragma unroll
        for (int m = 0; m < 4; m++)
            #pragma unroll
            for (int n = 0; n < 8; n++) {
                acc[m][n] = __builtin_amdgcn_mfma_f32_16x16x32_bf16(ah[m], bh[n], acc[m][n], 0, 0, 0);
                acc[m][n] = __builtin_amdgcn_mfma_f32_16x16x32_bf16(al[m], bh[n], acc[m][n], 0, 0, 0);
                acc[m][n] = __builtin_amdgcn_mfma_f32_16x16x32_bf16(ah[m], bl[n], acc[m][n], 0, 0, 0);
            }
        __syncthreads();
    }

    // epilogue: C layout col=lane&15, row=(lane>>4)*4+reg; writes fp32 h only
    int dbase = bnd + wc * 32 + (lane & 15);
    int rbase = bm + wr * 64 + ((lane >> 4) << 2);
    #pragma unroll
    for (int j = 0; j < 2; j++) {
        int d = dbase + j * 16;
        float cbr = b_ih[d] + b_hh[d];
        float cbz = b_ih[D + d] + b_hh[D + d];
        float bin = b_ih[2 * D + d];
        float bhn = b_hh[2 * D + d];
        #pragma unroll
        for (int m = 0; m < 4; m++) {
            #pragma unroll
            for (int q = 0; q < 4; q++) {
                int row = rbase + m * 16 + q;
                if (row < M) {
                    float r = sigm(acc[m][j][q] + cbr);
                    float z = sigm(acc[m][2 + j][q] + cbz);
                    float nn = tanhf(acc[m][4 + j][q] + bin + r * (acc[m][6 + j][q] + bhn));
                    float* hp = &h[(size_t)row * D + d];
                    float hv = *hp;
                    *hp = (1.f - z) * nn + z * hv;
                }
            }
        }
    }
}

// ---------------- readout + softmax ----------------
__global__ __launch_bounds__(256) void readout_kernel(const float* __restrict__ h,
                                                      const float* __restrict__ w_ro,
                                                      const float* __restrict__ b_ro,
                                                      float* __restrict__ out, int M) {
    __shared__ float ws_[D * K_OUT];
    for (int i = threadIdx.x; i < D * K_OUT; i += 256) ws_[i] = w_ro[i];
    __syncthreads();
    int group = threadIdx.x >> 5;
    int col   = threadIdx.x & 31;
    int node  = blockIdx.x * 8 + group;
    if (node >= M) return;
    float acc = b_ro[col];
    const float* hrow = &h[(size_t)node * D];
    #pragma unroll 8
    for (int k = 0; k < D; k++) acc += hrow[k] * ws_[k * K_OUT + col];
    float mx = acc;
    #pragma unroll
    for (int off = 16; off > 0; off >>= 1) mx = fmaxf(mx, __shfl_xor(mx, off, 32));
    float e = __expf(acc - mx);
    float s = e;
    #pragma unroll
    for (int off = 16; off > 0; off >>= 1) s += __shfl_xor(s, off, 32);
    out[(size_t)node * K_OUT + col] = e / s;
}

extern "C" void kernel_launch(void* const* d_in, const int* in_sizes, int n_in,
                              void* d_out, int out_size, void* d_ws, size_t ws_size,
                              hipStream_t stream) {
    const float* x      = (const float*)d_in[0];
    const int*   ei     = (const int*)d_in[1];
    const float* ea     = (const float*)d_in[2];
    const float* weight = (const float*)d_in[3];
    const float* w_ih   = (const float*)d_in[4];
    const float* w_hh   = (const float*)d_in[5];
    const float* b_ih   = (const float*)d_in[6];
    const float* b_hh   = (const float*)d_in[7];
    const float* w_ro   = (const float*)d_in[8];
    const float* b_ro   = (const float*)d_in[9];
    float* out = (float*)d_out;

    int N = in_sizes[0];          // 50000
    int E = in_sizes[2];          // 800000
    const int* src = ei;
    const int* dst = ei + E;

    size_t ND = (size_t)N * D;
    float* h = (float*)d_ws;
    unsigned short* A2 = (unsigned short*)(h + ND);                      // NPAD x 1024 bf16
    float* P = (float*)(A2 + (size_t)NPAD * 1024);                       // 4 x 256 x 768
    unsigned short* BT2 = (unsigned short*)(P + (size_t)L_LAYERS * 256 * 768); // 4 x 1024 x 1024
    float* sx = (float*)(BT2 + (size_t)L_LAYERS * 1024 * 1024);
    int* cnt = (int*)(sx + N);
    int* rowptr = cnt + (N + 1);
    int* cursor = rowptr + (N + 1);
    int* esrc = cursor + (N + 1);
    float* eval = (float*)(esrc + E);

    // ---- CSR build ----
    hipMemsetAsync(cnt, 0, (N + 1) * sizeof(int), stream);
    hist_kernel<<<1024, 256, 0, stream>>>(dst, cnt, E);
    scan_kernel<<<1, 1024, 0, stream>>>(cnt, rowptr, cursor, N);
    reorder_kernel<<<1024, 256, 0, stream>>>(src, dst, ea, cursor, esrc, eval, E);

    // ---- weight precompute ----
    prep_wih_kernel<<<dim3(4, 12, 4), 256, 0, stream>>>(weight, w_ih, P);
    pack_bt2_kernel<<<16384, 256, 0, stream>>>(P, w_hh, BT2);

    // ---- layer 0 (rank-2) ----
    sgather_kernel<<<(N + 255) / 256, 256, 0, stream>>>(x, rowptr, esrc, eval, sx, N);
    layer0_kernel<<<(N + 3) / 4, 256, 0, stream>>>(x, sx, P, w_hh, b_ih, b_hh, h, N);

    // ---- layers 1..3 ----
    dim3 gm(NPAD / 128, 4);
    int gather_blocks = (N * 64 + 255) / 256;
    for (int l = 1; l < L_LAYERS; l++) {
        gather_bf_kernel<<<gather_blocks, 256, 0, stream>>>(h, rowptr, esrc, eval, A2, N);
        gru_mfma_kernel<<<gm, 256, 0, stream>>>(A2, BT2 + (size_t)l * 1024 * 1024,
                                                b_ih, b_hh, h, N);
    }
    readout_kernel<<<(N + 7) / 8, 256, 0, stream>>>(h, w_ro, b_ro, out, N);
}

// Round 8
// 1478.040 us; speedup vs baseline: 9.7749x; 1.0859x over previous
//
#include <hip/hip_runtime.h>

#define D 256
#define K_OUT 32
#define L_LAYERS 4
#define NPAD 50048

typedef __attribute__((ext_vector_type(8))) short bf16x8;
typedef __attribute__((ext_vector_type(4))) float f32x4;
typedef __attribute__((address_space(3))) unsigned int lds_u32;
typedef const __attribute__((address_space(1))) unsigned int glb_u32;

__device__ __forceinline__ float sigm(float v) { return 1.f / (1.f + __expf(-v)); }
__device__ __forceinline__ unsigned short f2bf(float f) {
    unsigned u = __float_as_uint(f);
    u = u + 0x7fffu + ((u >> 16) & 1u);
    return (unsigned short)(u >> 16);
}
__device__ __forceinline__ float bf2f(unsigned short s) {
    return __uint_as_float(((unsigned)s) << 16);
}
__device__ __forceinline__ void gload16(const unsigned short* g, unsigned short* l) {
    __builtin_amdgcn_global_load_lds((glb_u32*)g, (lds_u32*)l, 16, 0, 0);
}

// ---------------- CSR build ----------------
__global__ __launch_bounds__(256) void hist_kernel(const int* __restrict__ dst,
                                                   int* __restrict__ cnt, int E) {
    int idx = blockIdx.x * blockDim.x + threadIdx.x;
    for (int e = idx; e < E; e += gridDim.x * blockDim.x)
        atomicAdd(&cnt[dst[e]], 1);
}

__global__ __launch_bounds__(1024) void scan_kernel(const int* __restrict__ cnt,
                                                    int* __restrict__ rowptr,
                                                    int* __restrict__ cursor, int n) {
    __shared__ int sdata[1024];
    int t = threadIdx.x;
    int chunk = (n + 1023) / 1024;
    int start = t * chunk;
    int end = start + chunk; if (end > n) end = n;
    int s = 0;
    for (int i = start; i < end; i++) s += cnt[i];
    sdata[t] = s;
    __syncthreads();
    for (int off = 1; off < 1024; off <<= 1) {
        int v = (t >= off) ? sdata[t - off] : 0;
        __syncthreads();
        sdata[t] += v;
        __syncthreads();
    }
    int base = sdata[t] - s;
    for (int i = start; i < end; i++) {
        rowptr[i] = base;
        cursor[i] = base;
        base += cnt[i];
    }
    if (end == n && start <= n) rowptr[n] = base;
}

__global__ __launch_bounds__(256) void reorder_kernel(const int* __restrict__ src,
                                                      const int* __restrict__ dst,
                                                      const float* __restrict__ ea,
                                                      int* __restrict__ cursor,
                                                      int* __restrict__ esrc,
                                                      float* __restrict__ eval, int E) {
    int idx = blockIdx.x * blockDim.x + threadIdx.x;
    for (int e = idx; e < E; e += gridDim.x * blockDim.x) {
        int slot = atomicAdd(&cursor[dst[e]], 1);
        esrc[slot] = src[e];
        eval[slot] = ea[e];
    }
}

// ---------------- P[l][k][c3] = (weight[l] @ w_ih^T)[k][c3], 256x768 per layer ----------------
__global__ __launch_bounds__(256) void prep_wih_kernel(const float* __restrict__ weight,
                                                       const float* __restrict__ w_ih,
                                                       float* __restrict__ P) {
    int l = blockIdx.z;
    const float* A = weight + (size_t)l * D * D;
    float* Cdst = P + (size_t)l * 256 * 768;
    __shared__ float As[32][64 + 4];
    __shared__ float Bs[32][64 + 4];
    int tid = threadIdx.x;
    int tx = tid & 15, ty = tid >> 4;
    int bk = blockIdx.x * 64;
    int bn = blockIdx.y * 64;
    float acc[4][4] = {};
    for (int jb = 0; jb < D; jb += 32) {
        #pragma unroll
        for (int i = 0; i < 2; i++) {
            int lin = tid + i * 256;
            int row = lin >> 3;
            int c4 = (lin & 7) << 2;
            float4 v = *(const float4*)&A[(size_t)(bk + row) * D + jb + c4];
            As[c4+0][row]=v.x; As[c4+1][row]=v.y; As[c4+2][row]=v.z; As[c4+3][row]=v.w;
            float4 w = *(const float4*)&w_ih[(size_t)(bn + row) * D + jb + c4];
            Bs[c4+0][row]=w.x; Bs[c4+1][row]=w.y; Bs[c4+2][row]=w.z; Bs[c4+3][row]=w.w;
        }
        __syncthreads();
        #pragma unroll
        for (int jj = 0; jj < 32; jj++) {
            float a[4], b[4];
            *(float4*)a = *(const float4*)&As[jj][ty*4];
            *(float4*)b = *(const float4*)&Bs[jj][tx*4];
            #pragma unroll
            for (int i = 0; i < 4; i++)
                #pragma unroll
                for (int j = 0; j < 4; j++)
                    acc[i][j] += a[i] * b[j];
        }
        __syncthreads();
    }
    #pragma unroll
    for (int i = 0; i < 4; i++)
        *(float4*)&Cdst[(size_t)(bk + ty*4 + i) * 768 + bn + tx*4] =
            make_float4(acc[i][0], acc[i][1], acc[i][2], acc[i][3]);
}

// ---------------- BT2[l][c][k2] bf16: c=g*256+d (g: r,z,ni,nh), k2<512 hi, >=512 lo ----------------
__global__ __launch_bounds__(256) void pack_bt2_kernel(const float* __restrict__ P,
                                                       const float* __restrict__ w_hh,
                                                       unsigned short* __restrict__ BT2) {
    long long idx = (long long)blockIdx.x * 256 + threadIdx.x;   // 4M total
    int l = (int)(idx >> 20);
    int rem = (int)(idx & 1048575);
    int c = rem >> 10;
    int k2 = rem & 1023;
    int g = c >> 8, d = c & 255;
    int k = k2 & 511;
    float val;
    if (k < 256) {
        val = (g == 0) ? P[(size_t)l * 196608 + (size_t)k * 768 + d]
            : (g == 1) ? P[(size_t)l * 196608 + (size_t)k * 768 + 256 + d]
            : (g == 2) ? P[(size_t)l * 196608 + (size_t)k * 768 + 512 + d]
            : 0.f;
    } else {
        int kk = k - 256;
        val = (g == 0) ? w_hh[(size_t)d * D + kk]
            : (g == 1) ? w_hh[(size_t)(256 + d) * D + kk]
            : (g == 3) ? w_hh[(size_t)(512 + d) * D + kk]
            : 0.f;
    }
    unsigned short hi = f2bf(val);
    BT2[idx] = (k2 < 512) ? hi : f2bf(val - bf2f(hi));
}

// ---------------- scalar gather: sx[n] = sum ea * x[src] ----------------
__global__ __launch_bounds__(256) void sgather_kernel(const float* __restrict__ x,
                                                      const int* __restrict__ rowptr,
                                                      const int* __restrict__ esrc,
                                                      const float* __restrict__ eval,
                                                      float* __restrict__ sx, int n) {
    int node = blockIdx.x * blockDim.x + threadIdx.x;
    if (node >= n) return;
    float s = 0.f;
    int end = rowptr[node + 1];
    for (int e = rowptr[node]; e < end; e++) s += eval[e] * x[esrc[e]];
    sx[node] = s;
}

// ---------------- layer 0: rank-2 + GRU epilogue, writes h ----------------
__global__ __launch_bounds__(256) void layer0_kernel(const float* __restrict__ x,
                                                     const float* __restrict__ sx,
                                                     const float* __restrict__ P0,
                                                     const float* __restrict__ w_hh,
                                                     const float* __restrict__ b_ih,
                                                     const float* __restrict__ b_hh,
                                                     float* __restrict__ hout, int M) {
    int node = blockIdx.x * 4 + (threadIdx.x >> 6);
    if (node >= M) return;
    int d0 = (threadIdx.x & 63) * 4;
    float sxn = sx[node], xn = x[node];
    float4 r0 = *(const float4*)&P0[d0];
    float4 z0 = *(const float4*)&P0[256 + d0];
    float4 n0 = *(const float4*)&P0[512 + d0];
    float r1[4], z1[4], n1[4];
    #pragma unroll
    for (int j = 0; j < 4; j++) {
        r1[j] = w_hh[(size_t)(d0 + j) * D];
        z1[j] = w_hh[(size_t)(256 + d0 + j) * D];
        n1[j] = w_hh[(size_t)(512 + d0 + j) * D];
    }
    float4 bir = *(const float4*)&b_ih[d0];
    float4 biz = *(const float4*)&b_ih[256 + d0];
    float4 bin = *(const float4*)&b_ih[512 + d0];
    float4 bhr = *(const float4*)&b_hh[d0];
    float4 bhz = *(const float4*)&b_hh[256 + d0];
    float4 bhn = *(const float4*)&b_hh[512 + d0];
    float rr[4] = {sxn*r0.x + xn*r1[0] + bir.x + bhr.x, sxn*r0.y + xn*r1[1] + bir.y + bhr.y,
                   sxn*r0.z + xn*r1[2] + bir.z + bhr.z, sxn*r0.w + xn*r1[3] + bir.w + bhr.w};
    float zz[4] = {sxn*z0.x + xn*z1[0] + biz.x + bhz.x, sxn*z0.y + xn*z1[1] + biz.y + bhz.y,
                   sxn*z0.z + xn*z1[2] + biz.z + bhz.z, sxn*z0.w + xn*z1[3] + biz.w + bhz.w};
    float ni[4] = {sxn*n0.x + bin.x, sxn*n0.y + bin.y, sxn*n0.z + bin.z, sxn*n0.w + bin.w};
    float nh[4] = {xn*n1[0] + bhn.x, xn*n1[1] + bhn.y, xn*n1[2] + bhn.z, xn*n1[3] + bhn.w};
    float o[4];
    #pragma unroll
    for (int j = 0; j < 4; j++) {
        float r = sigm(rr[j]);
        float z = sigm(zz[j]);
        float nn = tanhf(ni[j] + r * nh[j]);
        float hp = (d0 + j == 0) ? xn : 0.f;
        o[j] = (1.f - z) * nn + z * hp;
    }
    *(float4*)&hout[(size_t)node * D + d0] = make_float4(o[0], o[1], o[2], o[3]);
}

// ---------------- gather + fused h2bf (runs after gru completes; kernel boundary) ----------
__global__ __launch_bounds__(256) void gather_bf_kernel(const float* __restrict__ h,
                                                        const int* __restrict__ rowptr,
                                                        const int* __restrict__ esrc,
                                                        const float* __restrict__ eval,
                                                        unsigned short* __restrict__ A2, int n) {
    int node = (blockIdx.x * 256 + threadIdx.x) >> 6;
    int lane = threadIdx.x & 63;
    if (node >= n) return;
    int beg = rowptr[node], end = rowptr[node + 1];
    float4 acc = make_float4(0.f, 0.f, 0.f, 0.f);
    for (int e = beg; e < end; e++) {
        int s = esrc[e];
        float a = eval[e];
        float4 v = *(const float4*)&h[(size_t)s * D + lane * 4];
        acc.x += a * v.x; acc.y += a * v.y; acc.z += a * v.z; acc.w += a * v.w;
    }
    ushort4 hi = make_ushort4(f2bf(acc.x), f2bf(acc.y), f2bf(acc.z), f2bf(acc.w));
    ushort4 lo = make_ushort4(f2bf(acc.x - bf2f(hi.x)), f2bf(acc.y - bf2f(hi.y)),
                              f2bf(acc.z - bf2f(hi.z)), f2bf(acc.w - bf2f(hi.w)));
    *(ushort4*)&A2[(size_t)node * 1024 + lane * 4] = hi;
    *(ushort4*)&A2[(size_t)node * 1024 + 512 + lane * 4] = lo;
    float4 hv = *(const float4*)&h[(size_t)node * D + lane * 4];
    ushort4 hh = make_ushort4(f2bf(hv.x), f2bf(hv.y), f2bf(hv.z), f2bf(hv.w));
    ushort4 hl = make_ushort4(f2bf(hv.x - bf2f(hh.x)), f2bf(hv.y - bf2f(hh.y)),
                              f2bf(hv.z - bf2f(hh.z)), f2bf(hv.w - bf2f(hh.w)));
    *(ushort4*)&A2[(size_t)node * 1024 + 256 + lane * 4] = hh;
    *(ushort4*)&A2[(size_t)node * 1024 + 768 + lane * 4] = hl;
}

// ---------------- MFMA GRU v3: 2-phase prefetch dbuf + zero-gate skip ----------------
// Per K-chunk c (32 k2-cols): stage A_hi(8) A_lo(8) B_hi(12) B_lo(12) = 40 frags x 1KB.
// B gates staged: {r, z, ni} for c<8, {r, z, nh} for c>=8 (other plane is exactly zero).
// LDS 2 x 40KB dbuf; stage(c+1) issued BEFORE compute(c); one drain+barrier per iter.
__global__ __launch_bounds__(256, 2) void gru_mfma_kernel(const unsigned short* __restrict__ A2,
                                                          const unsigned short* __restrict__ BT2,
                                                          const float* __restrict__ b_ih,
                                                          const float* __restrict__ b_hh,
                                                          float* __restrict__ h, int M) {
    __shared__ unsigned short sm[2][20480];   // 80 KB
    int tid = threadIdx.x;
    int lane = tid & 63;
    int wid = tid >> 6;
    int wr = wid >> 1, wc = wid & 1;
    int bm = blockIdx.x * 128;
    int bnd = blockIdx.y * 64;

    // 10 staging frags per wave; base offsets (c and gate-2 adjust added in-loop)
    unsigned gbase[10];
    bool gA[10], gG2[10];
    #pragma unroll
    for (int ff = 0; ff < 10; ff++) {
        int f = wid * 10 + ff;
        unsigned row, cb;
        bool isA, isG2 = false;
        if (f < 8)       { row = bm + f * 16 + (lane & 15);        cb = 0;   isA = true; }
        else if (f < 16) { row = bm + (f - 8) * 16 + (lane & 15);  cb = 512; isA = true; }
        else if (f < 28) { int q = f - 16; int gs = q >> 2; int df = q & 3;
                           row = gs * 256 + bnd + df * 16 + (lane & 15); cb = 0; isA = false; isG2 = (gs == 2); }
        else             { int q = f - 28; int gs = q >> 2; int df = q & 3;
                           row = gs * 256 + bnd + df * 16 + (lane & 15); cb = 512; isA = false; isG2 = (gs == 2); }
        gbase[ff] = row * 1024u + cb + ((lane >> 4) << 3);
        gA[ff] = isA; gG2[ff] = isG2;
    }

    f32x4 acc[4][8];
    #pragma unroll
    for (int i = 0; i < 4; i++)
        #pragma unroll
        for (int j = 0; j < 8; j++)
            acc[i][j] = (f32x4){0.f, 0.f, 0.f, 0.f};

#define STAGE(C_, B_)                                                              \
    {                                                                              \
        _Pragma("unroll")                                                          \
        for (int ff = 0; ff < 10; ff++) {                                          \
            const unsigned short* gp = (gA[ff] ? A2 : BT2) + gbase[ff]             \
                + (C_) * 32 + ((gG2[ff] && (C_) >= 8) ? 262144u : 0u);             \
            gload16(gp, &sm[B_][(wid * 10 + ff) * 512]);                           \
        }                                                                          \
    }

#define KBODY(C_, NIOFF_)                                                          \
    {                                                                              \
        int cur = (C_) & 1;                                                        \
        if ((C_) < 15) STAGE((C_) + 1, cur ^ 1);                                   \
        bf16x8 ah[4], al[4], bh[6], bl[6];                                         \
        _Pragma("unroll")                                                          \
        for (int m = 0; m < 4; m++) {                                              \
            ah[m] = *(const bf16x8*)&sm[cur][(wr * 4 + m) * 512 + lane * 8];       \
            al[m] = *(const bf16x8*)&sm[cur][(8 + wr * 4 + m) * 512 + lane * 8];   \
        }                                                                          \
        _Pragma("unroll")                                                          \
        for (int j = 0; j < 6; j++) {                                              \
            int fb = 16 + (j >> 1) * 4 + wc * 2 + (j & 1);                         \
            bh[j] = *(const bf16x8*)&sm[cur][fb * 512 + lane * 8];                 \
            bl[j] = *(const bf16x8*)&sm[cur][(fb + 12) * 512 + lane * 8];          \
        }                                                                          \
        _Pragma("unroll")                                                          \
        for (int m = 0; m < 4; m++) {                                              \
            _Pragma("unroll")                                                      \
            for (int j = 0; j < 6; j++) {                                          \
                int na = (j < 4) ? j : (NIOFF_) + (j & 1);                         \
                acc[m][na] = __builtin_amdgcn_mfma_f32_16x16x32_bf16(ah[m], bh[j], acc[m][na], 0, 0, 0); \
                acc[m][na] = __builtin_amdgcn_mfma_f32_16x16x32_bf16(al[m], bh[j], acc[m][na], 0, 0, 0); \
                acc[m][na] = __builtin_amdgcn_mfma_f32_16x16x32_bf16(ah[m], bl[j], acc[m][na], 0, 0, 0); \
            }                                                                      \
        }                                                                          \
        __syncthreads();                                                           \
    }

    STAGE(0, 0);
    __syncthreads();
    #pragma unroll
    for (int cc = 0; cc < 8; cc++) KBODY(cc, 4)
    #pragma unroll
    for (int cc = 8; cc < 16; cc++) KBODY(cc, 6)
#undef STAGE
#undef KBODY

    // epilogue: C layout col=lane&15, row=(lane>>4)*4+reg; writes fp32 h only
    int rbase = bm + wr * 64 + ((lane >> 4) << 2);
    #pragma unroll
    for (int jj = 0; jj < 2; jj++) {
        int d = bnd + (wc * 2 + jj) * 16 + (lane & 15);
        float cbr = b_ih[d] + b_hh[d];
        float cbz = b_ih[D + d] + b_hh[D + d];
        float bin = b_ih[2 * D + d];
        float bhn = b_hh[2 * D + d];
        #pragma unroll
        for (int m = 0; m < 4; m++) {
            #pragma unroll
            for (int q = 0; q < 4; q++) {
                int row = rbase + m * 16 + q;
                if (row < M) {
                    float r = sigm(acc[m][jj][q] + cbr);
                    float z = sigm(acc[m][2 + jj][q] + cbz);
                    float nn = tanhf(acc[m][4 + jj][q] + bin + r * (acc[m][6 + jj][q] + bhn));
                    float* hp = &h[(size_t)row * D + d];
                    float hv = *hp;
                    *hp = (1.f - z) * nn + z * hv;
                }
            }
        }
    }
}

// ---------------- readout + softmax ----------------
__global__ __launch_bounds__(256) void readout_kernel(const float* __restrict__ h,
                                                      const float* __restrict__ w_ro,
                                                      const float* __restrict__ b_ro,
                                                      float* __restrict__ out, int M) {
    __shared__ float ws_[D * K_OUT];
    for (int i = threadIdx.x; i < D * K_OUT; i += 256) ws_[i] = w_ro[i];
    __syncthreads();
    int group = threadIdx.x >> 5;
    int col   = threadIdx.x & 31;
    int node  = blockIdx.x * 8 + group;
    if (node >= M) return;
    float acc = b_ro[col];
    const float* hrow = &h[(size_t)node * D];
    #pragma unroll 8
    for (int k = 0; k < D; k++) acc += hrow[k] * ws_[k * K_OUT + col];
    float mx = acc;
    #pragma unroll
    for (int off = 16; off > 0; off >>= 1) mx = fmaxf(mx, __shfl_xor(mx, off, 32));
    float e = __expf(acc - mx);
    float s = e;
    #pragma unroll
    for (int off = 16; off > 0; off >>= 1) s += __shfl_xor(s, off, 32);
    out[(size_t)node * K_OUT + col] = e / s;
}

extern "C" void kernel_launch(void* const* d_in, const int* in_sizes, int n_in,
                              void* d_out, int out_size, void* d_ws, size_t ws_size,
                              hipStream_t stream) {
    const float* x      = (const float*)d_in[0];
    const int*   ei     = (const int*)d_in[1];
    const float* ea     = (const float*)d_in[2];
    const float* weight = (const float*)d_in[3];
    const float* w_ih   = (const float*)d_in[4];
    const float* w_hh   = (const float*)d_in[5];
    const float* b_ih   = (const float*)d_in[6];
    const float* b_hh   = (const float*)d_in[7];
    const float* w_ro   = (const float*)d_in[8];
    const float* b_ro   = (const float*)d_in[9];
    float* out = (float*)d_out;

    int N = in_sizes[0];          // 50000
    int E = in_sizes[2];          // 800000
    const int* src = ei;
    const int* dst = ei + E;

    size_t ND = (size_t)N * D;
    float* h = (float*)d_ws;
    unsigned short* A2 = (unsigned short*)(h + ND);                      // NPAD x 1024 bf16
    float* P = (float*)(A2 + (size_t)NPAD * 1024);                       // 4 x 256 x 768
    unsigned short* BT2 = (unsigned short*)(P + (size_t)L_LAYERS * 256 * 768); // 4 x 1024 x 1024
    float* sx = (float*)(BT2 + (size_t)L_LAYERS * 1024 * 1024);
    int* cnt = (int*)(sx + N);
    int* rowptr = cnt + (N + 1);
    int* cursor = rowptr + (N + 1);
    int* esrc = cursor + (N + 1);
    float* eval = (float*)(esrc + E);

    // ---- CSR build ----
    hipMemsetAsync(cnt, 0, (N + 1) * sizeof(int), stream);
    hist_kernel<<<1024, 256, 0, stream>>>(dst, cnt, E);
    scan_kernel<<<1, 1024, 0, stream>>>(cnt, rowptr, cursor, N);
    reorder_kernel<<<1024, 256, 0, stream>>>(src, dst, ea, cursor, esrc, eval, E);

    // ---- weight precompute ----
    prep_wih_kernel<<<dim3(4, 12, 4), 256, 0, stream>>>(weight, w_ih, P);
    pack_bt2_kernel<<<16384, 256, 0, stream>>>(P, w_hh, BT2);

    // ---- layer 0 (rank-2) ----
    sgather_kernel<<<(N + 255) / 256, 256, 0, stream>>>(x, rowptr, esrc, eval, sx, N);
    layer0_kernel<<<(N + 3) / 4, 256, 0, stream>>>(x, sx, P, w_hh, b_ih, b_hh, h, N);

    // ---- layers 1..3 ----
    dim3 gm(NPAD / 128, 4);
    int gather_blocks = (N * 64 + 255) / 256;
    for (int l = 1; l < L_LAYERS; l++) {
        gather_bf_kernel<<<gather_blocks, 256, 0, stream>>>(h, rowptr, esrc, eval, A2, N);
        gru_mfma_kernel<<<gm, 256, 0, stream>>>(A2, BT2 + (size_t)l * 1024 * 1024,
                                                b_ih, b_hh, h, N);
    }
    readout_kernel<<<(N + 7) / 8, 256, 0, stream>>>(h, w_ro, b_ro, out, N);
}

// Round 9
// 1410.847 us; speedup vs baseline: 10.2404x; 1.0476x over previous
//
#include <hip/hip_runtime.h>

#define D 256
#define K_OUT 32
#define L_LAYERS 4
#define NPAD 50048

typedef __attribute__((ext_vector_type(8))) short bf16x8;
typedef __attribute__((ext_vector_type(4))) float f32x4;
typedef __attribute__((address_space(3))) unsigned int lds_u32;
typedef const __attribute__((address_space(1))) unsigned int glb_u32;

__device__ __forceinline__ float sigm(float v) { return 1.f / (1.f + __expf(-v)); }
__device__ __forceinline__ unsigned short f2bf(float f) {
    unsigned u = __float_as_uint(f);
    u = u + 0x7fffu + ((u >> 16) & 1u);
    return (unsigned short)(u >> 16);
}
__device__ __forceinline__ float bf2f(unsigned short s) {
    return __uint_as_float(((unsigned)s) << 16);
}
__device__ __forceinline__ void gload16(const unsigned short* g, unsigned short* l) {
    __builtin_amdgcn_global_load_lds((glb_u32*)g, (lds_u32*)l, 16, 0, 0);
}

// frag id f -> A2/BT2 offset (ushort units): 0-7 A_hi, 8-15 A_lo, 16-27 B_hi, 28-39 B_lo
__device__ __forceinline__ void frag_addr(int f, int bm, int bnd, int lane,
                                          unsigned& off, bool& isA, bool& isG2) {
    if (f < 8) {
        off = (unsigned)(bm + f * 16 + (lane & 15)) * 1024u + ((lane >> 4) << 3);
        isA = true; isG2 = false;
    } else if (f < 16) {
        off = (unsigned)(bm + (f - 8) * 16 + (lane & 15)) * 1024u + 512u + ((lane >> 4) << 3);
        isA = true; isG2 = false;
    } else if (f < 28) {
        int q = f - 16; int gs = q >> 2; int df = q & 3;
        off = (unsigned)(gs * 256 + bnd + df * 16 + (lane & 15)) * 1024u + ((lane >> 4) << 3);
        isA = false; isG2 = (gs == 2);
    } else {
        int q = f - 28; int gs = q >> 2; int df = q & 3;
        off = (unsigned)(gs * 256 + bnd + df * 16 + (lane & 15)) * 1024u + 512u + ((lane >> 4) << 3);
        isA = false; isG2 = (gs == 2);
    }
}

// ---------------- CSR build ----------------
__global__ __launch_bounds__(256) void hist_kernel(const int* __restrict__ dst,
                                                   int* __restrict__ cnt, int E) {
    int idx = blockIdx.x * blockDim.x + threadIdx.x;
    for (int e = idx; e < E; e += gridDim.x * blockDim.x)
        atomicAdd(&cnt[dst[e]], 1);
}

__global__ __launch_bounds__(1024) void scan_kernel(const int* __restrict__ cnt,
                                                    int* __restrict__ rowptr,
                                                    int* __restrict__ cursor, int n) {
    __shared__ int sdata[1024];
    int t = threadIdx.x;
    int chunk = (n + 1023) / 1024;
    int start = t * chunk;
    int end = start + chunk; if (end > n) end = n;
    int s = 0;
    for (int i = start; i < end; i++) s += cnt[i];
    sdata[t] = s;
    __syncthreads();
    for (int off = 1; off < 1024; off <<= 1) {
        int v = (t >= off) ? sdata[t - off] : 0;
        __syncthreads();
        sdata[t] += v;
        __syncthreads();
    }
    int base = sdata[t] - s;
    for (int i = start; i < end; i++) {
        rowptr[i] = base;
        cursor[i] = base;
        base += cnt[i];
    }
    if (end == n && start <= n) rowptr[n] = base;
}

__global__ __launch_bounds__(256) void reorder_kernel(const int* __restrict__ src,
                                                      const int* __restrict__ dst,
                                                      const float* __restrict__ ea,
                                                      int* __restrict__ cursor,
                                                      int* __restrict__ esrc,
                                                      float* __restrict__ eval, int E) {
    int idx = blockIdx.x * blockDim.x + threadIdx.x;
    for (int e = idx; e < E; e += gridDim.x * blockDim.x) {
        int slot = atomicAdd(&cursor[dst[e]], 1);
        esrc[slot] = src[e];
        eval[slot] = ea[e];
    }
}

// ---------------- P[l][k][c3] = (weight[l] @ w_ih^T)[k][c3], 256x768 per layer ----------------
__global__ __launch_bounds__(256) void prep_wih_kernel(const float* __restrict__ weight,
                                                       const float* __restrict__ w_ih,
                                                       float* __restrict__ P) {
    int l = blockIdx.z;
    const float* A = weight + (size_t)l * D * D;
    float* Cdst = P + (size_t)l * 256 * 768;
    __shared__ float As[32][64 + 4];
    __shared__ float Bs[32][64 + 4];
    int tid = threadIdx.x;
    int tx = tid & 15, ty = tid >> 4;
    int bk = blockIdx.x * 64;
    int bn = blockIdx.y * 64;
    float acc[4][4] = {};
    for (int jb = 0; jb < D; jb += 32) {
        #pragma unroll
        for (int i = 0; i < 2; i++) {
            int lin = tid + i * 256;
            int row = lin >> 3;
            int c4 = (lin & 7) << 2;
            float4 v = *(const float4*)&A[(size_t)(bk + row) * D + jb + c4];
            As[c4+0][row]=v.x; As[c4+1][row]=v.y; As[c4+2][row]=v.z; As[c4+3][row]=v.w;
            float4 w = *(const float4*)&w_ih[(size_t)(bn + row) * D + jb + c4];
            Bs[c4+0][row]=w.x; Bs[c4+1][row]=w.y; Bs[c4+2][row]=w.z; Bs[c4+3][row]=w.w;
        }
        __syncthreads();
        #pragma unroll
        for (int jj = 0; jj < 32; jj++) {
            float a[4], b[4];
            *(float4*)a = *(const float4*)&As[jj][ty*4];
            *(float4*)b = *(const float4*)&Bs[jj][tx*4];
            #pragma unroll
            for (int i = 0; i < 4; i++)
                #pragma unroll
                for (int j = 0; j < 4; j++)
                    acc[i][j] += a[i] * b[j];
        }
        __syncthreads();
    }
    #pragma unroll
    for (int i = 0; i < 4; i++)
        *(float4*)&Cdst[(size_t)(bk + ty*4 + i) * 768 + bn + tx*4] =
            make_float4(acc[i][0], acc[i][1], acc[i][2], acc[i][3]);
}

// ---------------- BT2[l][c][k2] bf16: c=g*256+d (g: r,z,ni,nh), k2<512 hi, >=512 lo ----------------
__global__ __launch_bounds__(256) void pack_bt2_kernel(const float* __restrict__ P,
                                                       const float* __restrict__ w_hh,
                                                       unsigned short* __restrict__ BT2) {
    long long idx = (long long)blockIdx.x * 256 + threadIdx.x;   // 4M total
    int l = (int)(idx >> 20);
    int rem = (int)(idx & 1048575);
    int c = rem >> 10;
    int k2 = rem & 1023;
    int g = c >> 8, d = c & 255;
    int k = k2 & 511;
    float val;
    if (k < 256) {
        val = (g == 0) ? P[(size_t)l * 196608 + (size_t)k * 768 + d]
            : (g == 1) ? P[(size_t)l * 196608 + (size_t)k * 768 + 256 + d]
            : (g == 2) ? P[(size_t)l * 196608 + (size_t)k * 768 + 512 + d]
            : 0.f;
    } else {
        int kk = k - 256;
        val = (g == 0) ? w_hh[(size_t)d * D + kk]
            : (g == 1) ? w_hh[(size_t)(256 + d) * D + kk]
            : (g == 3) ? w_hh[(size_t)(512 + d) * D + kk]
            : 0.f;
    }
    unsigned short hi = f2bf(val);
    BT2[idx] = (k2 < 512) ? hi : f2bf(val - bf2f(hi));
}

// ---------------- scalar gather: sx[n] = sum ea * x[src] ----------------
__global__ __launch_bounds__(256) void sgather_kernel(const float* __restrict__ x,
                                                      const int* __restrict__ rowptr,
                                                      const int* __restrict__ esrc,
                                                      const float* __restrict__ eval,
                                                      float* __restrict__ sx, int n) {
    int node = blockIdx.x * blockDim.x + threadIdx.x;
    if (node >= n) return;
    float s = 0.f;
    int end = rowptr[node + 1];
    for (int e = rowptr[node]; e < end; e++) s += eval[e] * x[esrc[e]];
    sx[node] = s;
}

// ---------------- layer 0: rank-2 + GRU epilogue, writes h ----------------
__global__ __launch_bounds__(256) void layer0_kernel(const float* __restrict__ x,
                                                     const float* __restrict__ sx,
                                                     const float* __restrict__ P0,
                                                     const float* __restrict__ w_hh,
                                                     const float* __restrict__ b_ih,
                                                     const float* __restrict__ b_hh,
                                                     float* __restrict__ hout, int M) {
    int node = blockIdx.x * 4 + (threadIdx.x >> 6);
    if (node >= M) return;
    int d0 = (threadIdx.x & 63) * 4;
    float sxn = sx[node], xn = x[node];
    float4 r0 = *(const float4*)&P0[d0];
    float4 z0 = *(const float4*)&P0[256 + d0];
    float4 n0 = *(const float4*)&P0[512 + d0];
    float r1[4], z1[4], n1[4];
    #pragma unroll
    for (int j = 0; j < 4; j++) {
        r1[j] = w_hh[(size_t)(d0 + j) * D];
        z1[j] = w_hh[(size_t)(256 + d0 + j) * D];
        n1[j] = w_hh[(size_t)(512 + d0 + j) * D];
    }
    float4 bir = *(const float4*)&b_ih[d0];
    float4 biz = *(const float4*)&b_ih[256 + d0];
    float4 bin = *(const float4*)&b_ih[512 + d0];
    float4 bhr = *(const float4*)&b_hh[d0];
    float4 bhz = *(const float4*)&b_hh[256 + d0];
    float4 bhn = *(const float4*)&b_hh[512 + d0];
    float rr[4] = {sxn*r0.x + xn*r1[0] + bir.x + bhr.x, sxn*r0.y + xn*r1[1] + bir.y + bhr.y,
                   sxn*r0.z + xn*r1[2] + bir.z + bhr.z, sxn*r0.w + xn*r1[3] + bir.w + bhr.w};
    float zz[4] = {sxn*z0.x + xn*z1[0] + biz.x + bhz.x, sxn*z0.y + xn*z1[1] + biz.y + bhz.y,
                   sxn*z0.z + xn*z1[2] + biz.z + bhz.z, sxn*z0.w + xn*z1[3] + biz.w + bhz.w};
    float ni[4] = {sxn*n0.x + bin.x, sxn*n0.y + bin.y, sxn*n0.z + bin.z, sxn*n0.w + bin.w};
    float nh[4] = {xn*n1[0] + bhn.x, xn*n1[1] + bhn.y, xn*n1[2] + bhn.z, xn*n1[3] + bhn.w};
    float o[4];
    #pragma unroll
    for (int j = 0; j < 4; j++) {
        float r = sigm(rr[j]);
        float z = sigm(zz[j]);
        float nn = tanhf(ni[j] + r * nh[j]);
        float hp = (d0 + j == 0) ? xn : 0.f;
        o[j] = (1.f - z) * nn + z * hp;
    }
    *(float4*)&hout[(size_t)node * D + d0] = make_float4(o[0], o[1], o[2], o[3]);
}

// ---------------- gather + fused h2bf (runs after gru completes; kernel boundary) ----------
__global__ __launch_bounds__(256) void gather_bf_kernel(const float* __restrict__ h,
                                                        const int* __restrict__ rowptr,
                                                        const int* __restrict__ esrc,
                                                        const float* __restrict__ eval,
                                                        unsigned short* __restrict__ A2, int n) {
    int node = (blockIdx.x * 256 + threadIdx.x) >> 6;
    int lane = threadIdx.x & 63;
    if (node >= n) return;
    int beg = rowptr[node], end = rowptr[node + 1];
    float4 acc = make_float4(0.f, 0.f, 0.f, 0.f);
    for (int e = beg; e < end; e++) {
        int s = esrc[e];
        float a = eval[e];
        float4 v = *(const float4*)&h[(size_t)s * D + lane * 4];
        acc.x += a * v.x; acc.y += a * v.y; acc.z += a * v.z; acc.w += a * v.w;
    }
    ushort4 hi = make_ushort4(f2bf(acc.x), f2bf(acc.y), f2bf(acc.z), f2bf(acc.w));
    ushort4 lo = make_ushort4(f2bf(acc.x - bf2f(hi.x)), f2bf(acc.y - bf2f(hi.y)),
                              f2bf(acc.z - bf2f(hi.z)), f2bf(acc.w - bf2f(hi.w)));
    *(ushort4*)&A2[(size_t)node * 1024 + lane * 4] = hi;
    *(ushort4*)&A2[(size_t)node * 1024 + 512 + lane * 4] = lo;
    float4 hv = *(const float4*)&h[(size_t)node * D + lane * 4];
    ushort4 hh = make_ushort4(f2bf(hv.x), f2bf(hv.y), f2bf(hv.z), f2bf(hv.w));
    ushort4 hl = make_ushort4(f2bf(hv.x - bf2f(hh.x)), f2bf(hv.y - bf2f(hh.y)),
                              f2bf(hv.z - bf2f(hh.z)), f2bf(hv.w - bf2f(hh.w)));
    *(ushort4*)&A2[(size_t)node * 1024 + 256 + lane * 4] = hh;
    *(ushort4*)&A2[(size_t)node * 1024 + 768 + lane * 4] = hl;
}

// ---------------- MFMA GRU v4: counted-vmcnt 4-sub-phase pipeline + XCD swizzle ----------
// Per chunk c: H0={A_hi(8),B_hi(12)}, H1={A_lo(8),B_lo(12)}; each wave stages 5+5 in FIFO order.
// iter: vmcnt(5)[H0 ready] bar -> STAGE(c+1) -> Ah*Bh(24) -> vmcnt(10)[H1 ready] bar
//       -> Al*Bh + Ah*Bl (48). Loads never drained to 0 mid-loop (catalog T4).
__global__ __launch_bounds__(256, 2) void gru_mfma_kernel(const unsigned short* __restrict__ A2,
                                                          const unsigned short* __restrict__ BT2,
                                                          const float* __restrict__ b_ih,
                                                          const float* __restrict__ b_hh,
                                                          float* __restrict__ h, int M) {
    __shared__ unsigned short sm[2][20480];   // 80 KB
    int tid = threadIdx.x;
    int lane = tid & 63;
    int wid = tid >> 6;
    int wr = wid >> 1, wc = wid & 1;

    // T1: bijective XCD swizzle — the 4 bnd-slices of slab g get bids {c, c+8, c+16, c+24}
    int bid = blockIdx.x;   // 0..1563
    int g, by;
    if (bid < 1536) {
        int ch = bid >> 5;
        int rem = bid & 31;
        g = ch * 8 + (rem & 7);
        by = rem >> 3;
    } else {
        int r = bid - 1536;
        g = 384 + (r >> 2);
        by = r & 3;
    }
    int bm = g * 128;
    int bnd = by * 64;

    // per-wave staging tables: 5 H0 frags + 5 H1 frags
    unsigned g0off[5], g1off[5];
    int slot0[5], slot1[5];
    bool g0A[5], g0G2[5], g1A[5], g1G2[5];
    #pragma unroll
    for (int i = 0; i < 5; i++) {
        int idx = wid * 5 + i;
        int f0 = (idx < 8) ? idx : idx + 8;        // H0: 0-7 (A_hi), 16-27 (B_hi)
        int f1 = (idx < 8) ? idx + 8 : idx + 20;   // H1: 8-15 (A_lo), 28-39 (B_lo)
        frag_addr(f0, bm, bnd, lane, g0off[i], g0A[i], g0G2[i]);
        frag_addr(f1, bm, bnd, lane, g1off[i], g1A[i], g1G2[i]);
        slot0[i] = f0; slot1[i] = f1;
    }

    f32x4 acc[4][8];
    #pragma unroll
    for (int i = 0; i < 4; i++)
        #pragma unroll
        for (int j = 0; j < 8; j++)
            acc[i][j] = (f32x4){0.f, 0.f, 0.f, 0.f};

    bf16x8 ah[4], al[4], bh[6], bl[6];

#define STAGE_H0(C_, B_)                                                           \
    { _Pragma("unroll")                                                            \
      for (int i = 0; i < 5; i++) {                                                \
        const unsigned short* gp = (g0A[i] ? A2 : BT2) + g0off[i]                  \
            + (C_) * 32 + ((g0G2[i] && (C_) >= 8) ? 262144u : 0u);                 \
        gload16(gp, &sm[B_][slot0[i] * 512]);                                      \
      } }
#define STAGE_H1(C_, B_)                                                           \
    { _Pragma("unroll")                                                            \
      for (int i = 0; i < 5; i++) {                                                \
        const unsigned short* gp = (g1A[i] ? A2 : BT2) + g1off[i]                  \
            + (C_) * 32 + ((g1G2[i] && (C_) >= 8) ? 262144u : 0u);                 \
        gload16(gp, &sm[B_][slot1[i] * 512]);                                      \
      } }

#define KBODY(C_, NIOFF_)                                                          \
    {   int cur = (C_) & 1;                                                        \
        asm volatile("s_waitcnt vmcnt(5)" ::: "memory");                           \
        __builtin_amdgcn_sched_barrier(0);                                         \
        __builtin_amdgcn_s_barrier();                                              \
        if ((C_) < 15) { STAGE_H0((C_) + 1, cur ^ 1); STAGE_H1((C_) + 1, cur ^ 1); } \
        _Pragma("unroll")                                                          \
        for (int m = 0; m < 4; m++)                                                \
            ah[m] = *(const bf16x8*)&sm[cur][(wr * 4 + m) * 512 + lane * 8];       \
        _Pragma("unroll")                                                          \
        for (int j = 0; j < 6; j++) {                                              \
            int fb = 16 + (j >> 1) * 4 + wc * 2 + (j & 1);                         \
            bh[j] = *(const bf16x8*)&sm[cur][fb * 512 + lane * 8];                 \
        }                                                                          \
        _Pragma("unroll")                                                          \
        for (int m = 0; m < 4; m++)                                                \
            _Pragma("unroll")                                                      \
            for (int j = 0; j < 6; j++) {                                          \
                int na = (j < 4) ? j : (NIOFF_) + (j & 1);                         \
                acc[m][na] = __builtin_amdgcn_mfma_f32_16x16x32_bf16(ah[m], bh[j], acc[m][na], 0, 0, 0); \
            }                                                                      \
        if ((C_) < 15) { asm volatile("s_waitcnt vmcnt(10)" ::: "memory"); }       \
        else           { asm volatile("s_waitcnt vmcnt(0)"  ::: "memory"); }       \
        __builtin_amdgcn_sched_barrier(0);                                         \
        __builtin_amdgcn_s_barrier();                                              \
        _Pragma("unroll")                                                          \
        for (int m = 0; m < 4; m++)                                                \
            al[m] = *(const bf16x8*)&sm[cur][(8 + wr * 4 + m) * 512 + lane * 8];   \
        _Pragma("unroll")                                                          \
        for (int j = 0; j < 6; j++) {                                              \
            int fb = 16 + (j >> 1) * 4 + wc * 2 + (j & 1);                         \
            bl[j] = *(const bf16x8*)&sm[cur][(fb + 12) * 512 + lane * 8];          \
        }                                                                          \
        _Pragma("unroll")                                                          \
        for (int m = 0; m < 4; m++)                                                \
            _Pragma("unroll")                                                      \
            for (int j = 0; j < 6; j++) {                                          \
                int na = (j < 4) ? j : (NIOFF_) + (j & 1);                         \
                acc[m][na] = __builtin_amdgcn_mfma_f32_16x16x32_bf16(al[m], bh[j], acc[m][na], 0, 0, 0); \
                acc[m][na] = __builtin_amdgcn_mfma_f32_16x16x32_bf16(ah[m], bl[j], acc[m][na], 0, 0, 0); \
            }                                                                      \
    }

    STAGE_H0(0, 0); STAGE_H1(0, 0);
    KBODY(0, 4)  KBODY(1, 4)  KBODY(2, 4)  KBODY(3, 4)
    KBODY(4, 4)  KBODY(5, 4)  KBODY(6, 4)  KBODY(7, 4)
    KBODY(8, 6)  KBODY(9, 6)  KBODY(10, 6) KBODY(11, 6)
    KBODY(12, 6) KBODY(13, 6) KBODY(14, 6) KBODY(15, 6)
#undef STAGE_H0
#undef STAGE_H1
#undef KBODY

    // epilogue: C layout col=lane&15, row=(lane>>4)*4+reg; writes fp32 h only
    int rbase = bm + wr * 64 + ((lane >> 4) << 2);
    #pragma unroll
    for (int jj = 0; jj < 2; jj++) {
        int d = bnd + (wc * 2 + jj) * 16 + (lane & 15);
        float cbr = b_ih[d] + b_hh[d];
        float cbz = b_ih[D + d] + b_hh[D + d];
        float bin = b_ih[2 * D + d];
        float bhn = b_hh[2 * D + d];
        #pragma unroll
        for (int m = 0; m < 4; m++) {
            #pragma unroll
            for (int q = 0; q < 4; q++) {
                int row = rbase + m * 16 + q;
                if (row < M) {
                    float r = sigm(acc[m][jj][q] + cbr);
                    float z = sigm(acc[m][2 + jj][q] + cbz);
                    float nn = tanhf(acc[m][4 + jj][q] + bin + r * (acc[m][6 + jj][q] + bhn));
                    float* hp = &h[(size_t)row * D + d];
                    float hv = *hp;
                    *hp = (1.f - z) * nn + z * hv;
                }
            }
        }
    }
}

// ---------------- readout + softmax (float4 hrow) ----------------
__global__ __launch_bounds__(256) void readout_kernel(const float* __restrict__ h,
                                                      const float* __restrict__ w_ro,
                                                      const float* __restrict__ b_ro,
                                                      float* __restrict__ out, int M) {
    __shared__ float ws_[D * K_OUT];
    for (int i = threadIdx.x; i < D * K_OUT; i += 256) ws_[i] = w_ro[i];
    __syncthreads();
    int group = threadIdx.x >> 5;
    int col   = threadIdx.x & 31;
    int node  = blockIdx.x * 8 + group;
    if (node >= M) return;
    float a0 = b_ro[col], a1 = 0.f, a2 = 0.f, a3 = 0.f;
    const float* hrow = &h[(size_t)node * D];
    #pragma unroll 4
    for (int k = 0; k < D; k += 4) {
        float4 hv = *(const float4*)&hrow[k];
        a0 += hv.x * ws_[(k + 0) * K_OUT + col];
        a1 += hv.y * ws_[(k + 1) * K_OUT + col];
        a2 += hv.z * ws_[(k + 2) * K_OUT + col];
        a3 += hv.w * ws_[(k + 3) * K_OUT + col];
    }
    float acc = (a0 + a1) + (a2 + a3);
    float mx = acc;
    #pragma unroll
    for (int off = 16; off > 0; off >>= 1) mx = fmaxf(mx, __shfl_xor(mx, off, 32));
    float e = __expf(acc - mx);
    float s = e;
    #pragma unroll
    for (int off = 16; off > 0; off >>= 1) s += __shfl_xor(s, off, 32);
    out[(size_t)node * K_OUT + col] = e / s;
}

extern "C" void kernel_launch(void* const* d_in, const int* in_sizes, int n_in,
                              void* d_out, int out_size, void* d_ws, size_t ws_size,
                              hipStream_t stream) {
    const float* x      = (const float*)d_in[0];
    const int*   ei     = (const int*)d_in[1];
    const float* ea     = (const float*)d_in[2];
    const float* weight = (const float*)d_in[3];
    const float* w_ih   = (const float*)d_in[4];
    const float* w_hh   = (const float*)d_in[5];
    const float* b_ih   = (const float*)d_in[6];
    const float* b_hh   = (const float*)d_in[7];
    const float* w_ro   = (const float*)d_in[8];
    const float* b_ro   = (const float*)d_in[9];
    float* out = (float*)d_out;

    int N = in_sizes[0];          // 50000
    int E = in_sizes[2];          // 800000
    const int* src = ei;
    const int* dst = ei + E;

    size_t ND = (size_t)N * D;
    float* h = (float*)d_ws;
    unsigned short* A2 = (unsigned short*)(h + ND);                      // NPAD x 1024 bf16
    float* P = (float*)(A2 + (size_t)NPAD * 1024);                       // 4 x 256 x 768
    unsigned short* BT2 = (unsigned short*)(P + (size_t)L_LAYERS * 256 * 768); // 4 x 1024 x 1024
    float* sx = (float*)(BT2 + (size_t)L_LAYERS * 1024 * 1024);
    int* cnt = (int*)(sx + N);
    int* rowptr = cnt + (N + 1);
    int* cursor = rowptr + (N + 1);
    int* esrc = cursor + (N + 1);
    float* eval = (float*)(esrc + E);

    // ---- CSR build ----
    hipMemsetAsync(cnt, 0, (N + 1) * sizeof(int), stream);
    hist_kernel<<<1024, 256, 0, stream>>>(dst, cnt, E);
    scan_kernel<<<1, 1024, 0, stream>>>(cnt, rowptr, cursor, N);
    reorder_kernel<<<1024, 256, 0, stream>>>(src, dst, ea, cursor, esrc, eval, E);

    // ---- weight precompute ----
    prep_wih_kernel<<<dim3(4, 12, 4), 256, 0, stream>>>(weight, w_ih, P);
    pack_bt2_kernel<<<16384, 256, 0, stream>>>(P, w_hh, BT2);

    // ---- layer 0 (rank-2) ----
    sgather_kernel<<<(N + 255) / 256, 256, 0, stream>>>(x, rowptr, esrc, eval, sx, N);
    layer0_kernel<<<(N + 3) / 4, 256, 0, stream>>>(x, sx, P, w_hh, b_ih, b_hh, h, N);

    // ---- layers 1..3 ----
    int nb = (NPAD / 128) * 4;    // 1564, 1D swizzled grid
    int gather_blocks = (N * 64 + 255) / 256;
    for (int l = 1; l < L_LAYERS; l++) {
        gather_bf_kernel<<<gather_blocks, 256, 0, stream>>>(h, rowptr, esrc, eval, A2, N);
        gru_mfma_kernel<<<nb, 256, 0, stream>>>(A2, BT2 + (size_t)l * 1024 * 1024,
                                                b_ih, b_hh, h, N);
    }
    readout_kernel<<<(N + 7) / 8, 256, 0, stream>>>(h, w_ro, b_ro, out, N);
}